// Round 6
// baseline (691.375 us; speedup 1.0000x reference)
//
#include <hip/hip_runtime.h>

// LLM block: B=2,S=2048,D=2048,H=16,KVH=8,HD=128,FF=5504, f32 in/out, bf16 MFMA compute.
// Workspace layout (bytes), peak ~137MB:
//   wqkv_bf16   [4096,2048]  @ 0
//   h/h2_bf16   [4096,2048]  @ 16777216
//   qkv_bf16    [4096,4096]  @ 33554432   (region reused later by wgu)
//   attn_out    [4096,2048]  @ 67108864
//   wo_bf16     [2048,2048]  @ 83886080
//   wgu_bf16    [11008,2048] @ 33554432   (interleaved: per 256-row group = 128 gate | 128 up)
//   act_bf16    [4096,5504]  @ 92274688
//   wdown_bf16  [2048,5504]  @ 0
//   x1 (f32 residual) lives in d_out.

#define DM 2048
#define SEQ 2048
#define HD 128
#define FF_ 5504
// 1/sqrt(128) * log2(e): attention runs softmax in exp2 domain.
#define QK_SCALE_L2E 0.12751744f

typedef __bf16 bf16x8 __attribute__((ext_vector_type(8)));
typedef float f32x4 __attribute__((ext_vector_type(4)));
typedef float f32x16 __attribute__((ext_vector_type(16)));
typedef unsigned short u16x8 __attribute__((ext_vector_type(8)));
typedef unsigned int u32x4 __attribute__((ext_vector_type(4)));

typedef __attribute__((address_space(1))) void* gas1;
typedef __attribute__((address_space(3))) void* las3;
#define GLDS16(g, s) __builtin_amdgcn_global_load_lds((gas1)(g), (las3)(s), 16, 0, 0)

static __device__ __forceinline__ float bf2f(unsigned short u) {
  union { unsigned int i; float f; } c; c.i = ((unsigned int)u) << 16; return c.f;
}
static __device__ __forceinline__ unsigned short f2bf(float f) {
  __bf16 b = (__bf16)f;
  return __builtin_bit_cast(unsigned short, b);
}
static __device__ __forceinline__ unsigned int pk2(float a, float b) {
  return (unsigned int)f2bf(a) | ((unsigned int)f2bf(b) << 16);
}
// native exp2 (v_exp_f32); __exp2f doesn't exist in HIP headers (r3 compile fail)
static __device__ __forceinline__ float fexp2(float x) { return exp2f(x); }
// async 16B global->VGPR load, invisible to the compiler's waitcnt tracking
// (completion enforced by the manual counted vmcnt + sched_barrier below).
static __device__ __forceinline__ void ldg_b128(u32x4& dst, const unsigned short* p) {
  asm volatile("global_load_dwordx4 %0, %1, off" : "=v"(dst) : "v"(p));
}

// ---------------- f32 -> bf16 convert (8 elems/thread, exact grid) ----------------
__global__ __launch_bounds__(256) void k_conv(const float* __restrict__ src,
                                              unsigned short* __restrict__ dst) {
  size_t i = (size_t)(blockIdx.x * 256 + threadIdx.x) * 8;
  float4 a = *(const float4*)&src[i];
  float4 b = *(const float4*)&src[i + 4];
  u16x8 o;
  o[0] = f2bf(a.x); o[1] = f2bf(a.y); o[2] = f2bf(a.z); o[3] = f2bf(a.w);
  o[4] = f2bf(b.x); o[5] = f2bf(b.y); o[6] = f2bf(b.z); o[7] = f2bf(b.w);
  *(u16x8*)&dst[i] = o;
}

// ---- gate/up interleaved convert: dst row r of group t: r<128 -> wg, else wu ----
__global__ __launch_bounds__(256) void k_conv_gu(const float* __restrict__ g,
                                                 const float* __restrict__ u,
                                                 unsigned short* __restrict__ dst) {
  int i = blockIdx.x * 256 + threadIdx.x;
  int row = i >> 8;
  int c8 = (i & 255) * 8;
  int t = row >> 8, r = row & 255;
  const float* src = (r < 128) ? (g + (size_t)(t * 128 + r) * DM + c8)
                               : (u + (size_t)(t * 128 + (r - 128)) * DM + c8);
  float4 a = *(const float4*)src;
  float4 b = *(const float4*)(src + 4);
  u16x8 o;
  o[0] = f2bf(a.x); o[1] = f2bf(a.y); o[2] = f2bf(a.z); o[3] = f2bf(a.w);
  o[4] = f2bf(b.x); o[5] = f2bf(b.y); o[6] = f2bf(b.z); o[7] = f2bf(b.w);
  *(u16x8*)&dst[(size_t)row * DM + c8] = o;
}

// ---------------- RMSNorm: one block per row (D=2048, 8 f32/thread) ----------------
__global__ __launch_bounds__(256) void k_rmsnorm(const float* __restrict__ x,
                                                 const float* __restrict__ g,
                                                 unsigned short* __restrict__ out) {
  int row = blockIdx.x, tid = threadIdx.x;
  const float* xr = x + (size_t)row * DM;
  float4 a = *(const float4*)&xr[tid * 8];
  float4 b = *(const float4*)&xr[tid * 8 + 4];
  float ss = a.x * a.x + a.y * a.y + a.z * a.z + a.w * a.w +
             b.x * b.x + b.y * b.y + b.z * b.z + b.w * b.w;
#pragma unroll
  for (int off = 32; off > 0; off >>= 1) ss += __shfl_xor(ss, off, 64);
  __shared__ float red[4];
  if ((tid & 63) == 0) red[tid >> 6] = ss;
  __syncthreads();
  float rs = rsqrtf((red[0] + red[1] + red[2] + red[3]) * (1.0f / DM) + 1e-5f);
  float4 ga = *(const float4*)&g[tid * 8];
  float4 gb = *(const float4*)&g[tid * 8 + 4];
  u16x8 o;
  o[0] = f2bf(a.x * rs * ga.x); o[1] = f2bf(a.y * rs * ga.y);
  o[2] = f2bf(a.z * rs * ga.z); o[3] = f2bf(a.w * rs * ga.w);
  o[4] = f2bf(b.x * rs * gb.x); o[5] = f2bf(b.y * rs * gb.y);
  o[6] = f2bf(b.z * rs * gb.z); o[7] = f2bf(b.w * rs * gb.w);
  *(u16x8*)&out[(size_t)row * DM + tid * 8] = o;
}

// ---------------- RoPE in-place on qkv buffer (q cols 0..2047, k cols 2048..3071) ----
__global__ __launch_bounds__(256) void k_rope(unsigned short* __restrict__ qkv,
                                              const float* __restrict__ cosT,
                                              const float* __restrict__ sinT) {
  int idx = blockIdx.x * 256 + threadIdx.x;
  int j = idx & 63;
  int hh = (idx >> 6) % 24;
  int tok = idx / (64 * 24);
  int s = tok & (SEQ - 1);
  int colbase = (hh < 16) ? hh * HD : DM + (hh - 16) * HD;
  unsigned short* p = qkv + (size_t)tok * 4096 + colbase;
  float lo = bf2f(p[j]), hi = bf2f(p[j + 64]);
  const float* cr = cosT + (size_t)s * HD;
  const float* sr = sinT + (size_t)s * HD;
  float nl = lo * cr[j] - hi * sr[j];
  float nh = hi * cr[j + 64] + lo * sr[j + 64];
  if (hh < 16) { nl *= QK_SCALE_L2E; nh *= QK_SCALE_L2E; }  // fold scale*log2e into q
  p[j] = f2bf(nl);
  p[j + 64] = f2bf(nh);
}

// ---------------- deep-pipelined GEMM: C[M,N] = A[M,K] * Bt[N,K]^T --------------------
// r6 structure: A staged in LDS (4 buffers x 16KB, depth-3, swizzled per r4 fix);
// B (weights) loaded straight to VGPRs via asm global_load_dwordx4, prefetch depth 1
// (L2-hot panels), two named reg sets alternated by step-2 loop unroll (rule #20).
// ONE barrier + ONE counted vmcnt per K-tile. The single s_waitcnt vmcnt(W) +
// sched_barrier(0) (rule #18) before the MFMA cluster guarantees BOTH B(kt) in regs
// and A(kt+1) in LDS. W derivation (issue order: loadB first, then stageA, per window):
//   newer-than-B(kt)  = stageA(kt+2)[2] + loadB(kt+1)[NF] + stageA(kt+3)[2] = NF+4
//   newer-than-A(kt+1)= 2NF+4 >= NF+4  -> W0 = NF+4; tails NF+2 / NF / 0.
template <int BN, int EPI>
__global__ __launch_bounds__(512, 2) void k_gemm8(
    const unsigned short* __restrict__ A, const unsigned short* __restrict__ Bt,
    unsigned short* __restrict__ outB, float* __restrict__ outF,
    const float* __restrict__ res, int N, int K) {
  constexpr int NF = BN / 64;            // B frags (and asm loads) per wave per K-tile
  __shared__ __attribute__((aligned(16))) unsigned char smem[4 * 16384];  // A only

  const int tid = threadIdx.x, w = tid >> 6, l = tid & 63;
  const int wr = w >> 2, wc = w & 3, lr = l & 15, lg = l >> 4;
  const int nwg = gridDim.x, bid = blockIdx.x;
  const int bswz = (bid & 7) * (nwg >> 3) + (bid >> 3);
  const int mt = bswz & 15, nt = bswz >> 4;
  const int m0 = mt * 256, n0 = nt * BN;
  const int nk = K >> 5;                 // BK=32; nk even for all our shapes

  const int srow = w * 16 + (l >> 2);
  const int sg8 = ((l & 3) ^ ((l >> 3) & 3)) * 8;   // pre-swizzle: g ^ ((row>>1)&3)
  const unsigned short* Asrc = A + (size_t)(m0 + srow) * K + sg8;
  const int aoff = (wr * 128 + lr) * 64 + ((lg ^ ((lr >> 1) & 3)) << 4);
  const unsigned short* Bb = Bt + (size_t)(n0 + wc * (BN / 4) + lr) * K + lg * 8;

  auto stageA = [&](int kt) {
    unsigned char* bb = smem + (kt & 3) * 16384;
#pragma unroll
    for (int i = 0; i < 2; i++)
      GLDS16(Asrc + (size_t)i * 128 * K + kt * 32, bb + (i * 512 + w * 64) * 16);
  };

  f32x4 acc[8][NF] = {};
  u32x4 b0[NF], b1[NF];

  // prologue: B(0) to regs, stage A(0..2); publish A(0)
#pragma unroll
  for (int n = 0; n < NF; n++) ldg_b128(b0[n], Bb + (size_t)n * 16 * K);
  stageA(0); stageA(1); stageA(2);
  asm volatile("s_waitcnt vmcnt(4)" ::: "memory");   // A(0): exactly 4 newer (A1,A2)
  __builtin_amdgcn_s_barrier();

#define GBODY(KT, CUR, NXT, W)                                                    \
  {                                                                               \
    unsigned char* ba = smem + ((KT) & 3) * 16384;                                \
    bf16x8 am[8];                                                                 \
    _Pragma("unroll") for (int m = 0; m < 8; m++)                                 \
        am[m] = *(const bf16x8*)(ba + aoff + m * 1024);                           \
    if ((KT) + 1 < nk) {                                                          \
      _Pragma("unroll") for (int n = 0; n < NF; n++)                              \
          ldg_b128(NXT[n], Bb + (size_t)n * 16 * K + ((KT) + 1) * 32);            \
    }                                                                             \
    if ((KT) + 3 < nk) stageA((KT) + 3);                                          \
    asm volatile("s_waitcnt vmcnt(%0)" ::"i"(W) : "memory");                      \
    __builtin_amdgcn_sched_barrier(0);                                            \
    __builtin_amdgcn_s_setprio(1);                                                \
    _Pragma("unroll") for (int m = 0; m < 8; m++)                                 \
      _Pragma("unroll") for (int n = 0; n < NF; n++)                              \
          acc[m][n] = __builtin_amdgcn_mfma_f32_16x16x32_bf16(                    \
              am[m], __builtin_bit_cast(bf16x8, CUR[n]), acc[m][n], 0, 0, 0);     \
    __builtin_amdgcn_s_setprio(0);                                                \
    __builtin_amdgcn_s_barrier();                                                 \
  }

  for (int kt = 0; kt < nk - 4; kt += 2) {
    GBODY(kt, b0, b1, NF + 4);
    GBODY(kt + 1, b1, b0, NF + 4);
  }
  GBODY(nk - 4, b0, b1, NF + 4);
  GBODY(nk - 3, b1, b0, NF + 2);
  GBODY(nk - 2, b0, b1, NF);
  GBODY(nk - 1, b1, b0, 0);
#undef GBODY

  const int rbase = wr * 128 + lg * 4;
  const int cbase = wc * (BN / 4) + lr;
  if constexpr (EPI == 0) {
#pragma unroll
    for (int m = 0; m < 8; m++)
#pragma unroll
      for (int n = 0; n < NF; n++)
#pragma unroll
        for (int j = 0; j < 4; j++)
          outB[(size_t)(m0 + rbase + m * 16 + j) * N + n0 + cbase + n * 16] =
              f2bf(acc[m][n][j]);
  } else if constexpr (EPI == 1) {
#pragma unroll
    for (int m = 0; m < 8; m++)
#pragma unroll
      for (int n = 0; n < NF; n++)
#pragma unroll
        for (int j = 0; j < 4; j++) {
          size_t o = (size_t)(m0 + rbase + m * 16 + j) * N + n0 + cbase + n * 16;
          outF[o] = res[o] + acc[m][n][j];
        }
  } else {
    // gateup epilogue, 64KB scratch: two 128-row halves. Waves wr==half: wc<2 hold
    // gate (cols 0..127), wc>=2 hold up of the same ff columns.
    float* gl = (float*)smem;            // [128][128] f32
    const int ab = n0 >> 1;
#pragma unroll
    for (int half = 0; half < 2; half++) {
      if (wr == half && wc < 2) {
#pragma unroll
        for (int m = 0; m < 8; m++)
#pragma unroll
          for (int n = 0; n < NF; n++)
#pragma unroll
            for (int j = 0; j < 4; j++)
              gl[(m * 16 + lg * 4 + j) * 128 + wc * 64 + n * 16 + lr] = acc[m][n][j];
      }
      __syncthreads();
      if (wr == half && wc >= 2) {
#pragma unroll
        for (int m = 0; m < 8; m++)
#pragma unroll
          for (int n = 0; n < NF; n++)
#pragma unroll
            for (int j = 0; j < 4; j++) {
              int rl = m * 16 + lg * 4 + j;
              int cl = (wc - 2) * 64 + n * 16 + lr;
              float g = gl[rl * 128 + cl];
              float s = g / (1.0f + __expf(-g));
              outB[(size_t)(m0 + half * 128 + rl) * FF_ + ab + cl] = f2bf(s * acc[m][n][j]);
            }
      }
      __syncthreads();
    }
  }
}

// ---------------- causal GQA flash attention, 32x32 swapped-QK structure --------------
__global__ __launch_bounds__(256) void k_attn2(const unsigned short* __restrict__ qkv,
                                               unsigned short* __restrict__ out) {
  __shared__ __attribute__((aligned(16))) unsigned short lK[2][64 * 128];
  __shared__ __attribute__((aligned(16))) unsigned short lV[2][128 * 64];
  const float NEG = -3.0e38f;
  int bx = blockIdx.x;
  int qtile = 15 - (bx >> 5);          // heaviest q-tiles dispatched first
  int hb = bx & 31;
  int h = hb & 15, b = hb >> 4;
  int q0 = qtile * 128;
  int tid = threadIdx.x, w = tid >> 6, l = tid & 63;
  int l31 = l & 31, half2 = l >> 5;
  const unsigned short* base = qkv + (size_t)b * SEQ * 4096;
  const unsigned short* Kp = base + 2048 + (h >> 1) * HD;
  const unsigned short* Vp = base + 3072 + (h >> 1) * HD;
  const int qw = q0 + w * 32;

  bf16x8 qf[8];
  {
    const unsigned short* qrow = base + (size_t)(qw + l31) * 4096 + h * HD + half2 * 8;
#pragma unroll
    for (int d = 0; d < 8; d++) qf[d] = *(const bf16x8*)(qrow + d * 16);
  }

  f32x16 oacc[4] = {};
  float mrow = NEG, lsum = 0.0f;

  const int vp = tid & 31, vdc = tid >> 5;
  u16x8 va0, va1, vb0, vb1;

  auto stageK = [&](int t) {
    unsigned char* dst = (unsigned char*)lK[t & 1];
#pragma unroll
    for (int i = 0; i < 4; i++) {
      int c = i * 256 + tid;
      int row = c >> 4;
      int g = (c & 15) ^ (row & 7);
      GLDS16(Kp + (size_t)(t * 64 + row) * 4096 + g * 8, dst + (i * 256 + w * 64) * 16);
    }
  };
  auto loadV = [&](int t) {
    const unsigned short* vr = Vp + (size_t)(t * 64 + vp * 2) * 4096 + vdc * 16;
    va0 = *(const u16x8*)(vr);
    va1 = *(const u16x8*)(vr + 8);
    vb0 = *(const u16x8*)(vr + 4096);
    vb1 = *(const u16x8*)(vr + 4096 + 8);
  };

  const int nt = (q0 >> 6) + 2;
  stageK(0);
  loadV(0);

  for (int t = 0; t < nt; t++) {
    __syncthreads();
    {
      unsigned char* lv = (unsigned char*)lV[t & 1];
#pragma unroll
      for (int j = 0; j < 16; j++) {
        int dd = vdc * 16 + j;
        unsigned short lo = (j < 8) ? va0[j] : va1[j - 8];
        unsigned short hi = (j < 8) ? vb0[j] : vb1[j - 8];
        unsigned int pkv = (unsigned int)lo | ((unsigned int)hi << 16);
        *(unsigned int*)(lv + dd * 128 + (((vp >> 2) ^ (dd & 7)) * 16) + (vp & 3) * 4) = pkv;
      }
    }
    __syncthreads();
    if (t + 1 < nt) { stageK(t + 1); loadV(t + 1); }
    const int kv0 = t * 64;
    if (kv0 <= qw + 31) {
      f32x16 sc[2] = {};
      const unsigned char* lk = (const unsigned char*)lK[t & 1];
#pragma unroll
      for (int hh = 0; hh < 2; hh++) {
        int kk = hh * 32 + l31;
        const unsigned char* krow = lk + kk * 256;
#pragma unroll
        for (int d = 0; d < 8; d++) {
          bf16x8 kf = *(const bf16x8*)(krow + (((d * 2 + half2) ^ (kk & 7)) * 16));
          sc[hh] = __builtin_amdgcn_mfma_f32_32x32x16_bf16(kf, qf[d], sc[hh], 0, 0, 0);
        }
      }
      const int qa = qw + l31;
      if (kv0 + 63 > qw) {
#pragma unroll
        for (int hh = 0; hh < 2; hh++)
#pragma unroll
          for (int r = 0; r < 16; r++) {
            int kva = kv0 + hh * 32 + (r & 3) + 8 * (r >> 2) + 4 * half2;
            if (kva > qa) sc[hh][r] = NEG;
          }
      }
      float mx = sc[0][0];
#pragma unroll
      for (int r = 1; r < 16; r++) mx = fmaxf(mx, sc[0][r]);
#pragma unroll
      for (int r = 0; r < 16; r++) mx = fmaxf(mx, sc[1][r]);
      mx = fmaxf(mx, __shfl_xor(mx, 32));
      bool ok = (mx <= mrow + 11.0f);
      if (__ballot(ok) != ~0ull) {
        float mnew = fmaxf(mrow, mx);
        float fct = fexp2(mrow - mnew);
        mrow = mnew;
        lsum *= fct;
#pragma unroll
        for (int r = 0; r < 16; r++) {
          int rr = (r & 3) + 8 * (r >> 2) + 4 * half2;
          float fr = __shfl(fct, rr);
#pragma unroll
          for (int d = 0; d < 4; d++) oacc[d][r] *= fr;
        }
      }
      float ps = 0.0f;
#pragma unroll
      for (int hh = 0; hh < 2; hh++)
#pragma unroll
        for (int r = 0; r < 16; r++) {
          float e = fexp2(sc[hh][r] - mrow);
          sc[hh][r] = e;
          ps += e;
        }
      ps += __shfl_xor(ps, 32);
      lsum += ps;
      const unsigned char* lv = (const unsigned char*)lV[t & 1];
#pragma unroll
      for (int s = 0; s < 4; s++) {
        const int hh = s >> 1;
        const int r0 = (s & 1) * 8;
        unsigned int lo0, lo1, hi0, hi1;
        if (hh == 0) {
          lo0 = pk2(sc[0][r0 + 0], sc[0][r0 + 1]); lo1 = pk2(sc[0][r0 + 2], sc[0][r0 + 3]);
          hi0 = pk2(sc[0][r0 + 4], sc[0][r0 + 5]); hi1 = pk2(sc[0][r0 + 6], sc[0][r0 + 7]);
        } else {
          lo0 = pk2(sc[1][r0 + 0], sc[1][r0 + 1]); lo1 = pk2(sc[1][r0 + 2], sc[1][r0 + 3]);
          hi0 = pk2(sc[1][r0 + 4], sc[1][r0 + 5]); hi1 = pk2(sc[1][r0 + 6], sc[1][r0 + 7]);
        }
        unsigned int s0 = half2 ? lo0 : hi0, s1 = half2 ? lo1 : hi1;
        unsigned int rc0 = (unsigned int)__shfl_xor((int)s0, 32);
        unsigned int rc1 = (unsigned int)__shfl_xor((int)s1, 32);
        u32x4 fr;
        fr[0] = half2 ? rc0 : lo0; fr[1] = half2 ? rc1 : lo1;
        fr[2] = half2 ? hi0 : rc0; fr[3] = half2 ? hi1 : rc1;
        bf16x8 pa = __builtin_bit_cast(bf16x8, fr);
#pragma unroll
        for (int d = 0; d < 4; d++) {
          int dd = d * 32 + l31;
          bf16x8 vf = *(const bf16x8*)(lv + dd * 128 + (((s * 2 + half2) ^ (dd & 7)) * 16));
          oacc[d] = __builtin_amdgcn_mfma_f32_32x32x16_bf16(pa, vf, oacc[d], 0, 0, 0);
        }
      }
    }
  }
  float inv = 1.0f / lsum;
#pragma unroll
  for (int r = 0; r < 16; r++) {
    int rr = (r & 3) + 8 * (r >> 2) + 4 * half2;
    float ir = __shfl(inv, rr);
    size_t ob = ((size_t)(b * SEQ + qw + rr)) * 2048 + h * HD;
#pragma unroll
    for (int d = 0; d < 4; d++)
      out[ob + d * 32 + l31] = f2bf(oacc[d][r] * ir);
  }
}

// ---------------- launcher -------------------------------------------------------------
extern "C" void kernel_launch(void* const* d_in, const int* in_sizes, int n_in,
                              void* d_out, int out_size, void* d_ws, size_t ws_size,
                              hipStream_t stream) {
  const float* x = (const float*)d_in[0];
  const float* cosT = (const float*)d_in[1];
  const float* sinT = (const float*)d_in[2];
  const float* wq = (const float*)d_in[3];
  const float* wk = (const float*)d_in[4];
  const float* wv = (const float*)d_in[5];
  const float* wo = (const float*)d_in[6];
  const float* wg = (const float*)d_in[7];
  const float* wu = (const float*)d_in[8];
  const float* wd = (const float*)d_in[9];
  const float* g1 = (const float*)d_in[10];
  const float* g2 = (const float*)d_in[11];
  float* out = (float*)d_out;
  char* ws = (char*)d_ws;

  unsigned short* wqkv = (unsigned short*)(ws + 0);
  unsigned short* hbuf = (unsigned short*)(ws + 16777216);
  unsigned short* qkv = (unsigned short*)(ws + 33554432);
  unsigned short* attn_o = (unsigned short*)(ws + 67108864);
  unsigned short* wo_bf = (unsigned short*)(ws + 83886080);
  unsigned short* wgu = (unsigned short*)(ws + 33554432);
  unsigned short* act = (unsigned short*)(ws + 92274688);
  unsigned short* wdown = (unsigned short*)(ws + 0);

  // ---- attention sub-block ----
  k_conv<<<2048, 256, 0, stream>>>(wq, wqkv);
  k_conv<<<1024, 256, 0, stream>>>(wk, wqkv + 4194304);
  k_conv<<<1024, 256, 0, stream>>>(wv, wqkv + 6291456);
  k_rmsnorm<<<4096, 256, 0, stream>>>(x, g1, hbuf);
  k_gemm8<256, 0><<<256, 512, 0, stream>>>(hbuf, wqkv, qkv, nullptr, nullptr,
                                           4096, 2048);
  k_rope<<<24576, 256, 0, stream>>>(qkv, cosT, sinT);
  k_attn2<<<512, 256, 0, stream>>>(qkv, attn_o);
  k_conv<<<2048, 256, 0, stream>>>(wo, wo_bf);
  k_gemm8<128, 1><<<256, 512, 0, stream>>>(attn_o, wo_bf, nullptr, out, x,
                                           2048, 2048);
  // ---- SwiGLU MLP sub-block ----
  k_rmsnorm<<<4096, 256, 0, stream>>>(out, g2, hbuf);
  k_conv_gu<<<11008, 256, 0, stream>>>(wg, wu, wgu);
  k_gemm8<256, 2><<<688, 512, 0, stream>>>(hbuf, wgu, act, nullptr, nullptr,
                                           11008, 2048);
  k_conv<<<5504, 256, 0, stream>>>(wd, wdown);
  k_gemm8<128, 1><<<256, 512, 0, stream>>>(act, wdown, nullptr, out, out,
                                           2048, 5504);
}

// Round 7
// 623.319 us; speedup vs baseline: 1.1092x; 1.1092x over previous
//
#include <hip/hip_runtime.h>

// LLM block: B=2,S=2048,D=2048,H=16,KVH=8,HD=128,FF=5504, f32 in/out, bf16 MFMA compute.
// Workspace layout (bytes), peak ~137MB:
//   wqkv_bf16   [4096,2048]  @ 0
//   h/h2_bf16   [4096,2048]  @ 16777216
//   qkv_bf16    [4096,4096]  @ 33554432   (region reused later by wgu)
//   attn_out    [4096,2048]  @ 67108864
//   wo_bf16     [2048,2048]  @ 83886080
//   wgu_bf16    [11008,2048] @ 33554432   (interleaved: per 256-row group = 128 gate | 128 up)
//   act_bf16    [4096,5504]  @ 92274688
//   wdown_bf16  [2048,5504]  @ 0
//   x1 (f32 residual) lives in d_out.

#define DM 2048
#define SEQ 2048
#define HD 128
#define FF_ 5504
// 1/sqrt(128) * log2(e): attention runs softmax in exp2 domain.
#define QK_SCALE_L2E 0.12751744f

typedef __bf16 bf16x8 __attribute__((ext_vector_type(8)));
typedef float f32x4 __attribute__((ext_vector_type(4)));
typedef float f32x16 __attribute__((ext_vector_type(16)));
typedef unsigned short u16x8 __attribute__((ext_vector_type(8)));
typedef unsigned int u32x4 __attribute__((ext_vector_type(4)));

typedef __attribute__((address_space(1))) void* gas1;
typedef __attribute__((address_space(3))) void* las3;
#define GLDS16(g, s) __builtin_amdgcn_global_load_lds((gas1)(g), (las3)(s), 16, 0, 0)

static __device__ __forceinline__ float bf2f(unsigned short u) {
  union { unsigned int i; float f; } c; c.i = ((unsigned int)u) << 16; return c.f;
}
static __device__ __forceinline__ unsigned short f2bf(float f) {
  __bf16 b = (__bf16)f;
  return __builtin_bit_cast(unsigned short, b);
}
static __device__ __forceinline__ unsigned int pk2(float a, float b) {
  return (unsigned int)f2bf(a) | ((unsigned int)f2bf(b) << 16);
}
// native exp2 (v_exp_f32); __exp2f doesn't exist in HIP headers (r3 compile fail)
static __device__ __forceinline__ float fexp2(float x) { return exp2f(x); }

// ---------------- f32 -> bf16 convert (8 elems/thread, exact grid) ----------------
__global__ __launch_bounds__(256) void k_conv(const float* __restrict__ src,
                                              unsigned short* __restrict__ dst) {
  size_t i = (size_t)(blockIdx.x * 256 + threadIdx.x) * 8;
  float4 a = *(const float4*)&src[i];
  float4 b = *(const float4*)&src[i + 4];
  u16x8 o;
  o[0] = f2bf(a.x); o[1] = f2bf(a.y); o[2] = f2bf(a.z); o[3] = f2bf(a.w);
  o[4] = f2bf(b.x); o[5] = f2bf(b.y); o[6] = f2bf(b.z); o[7] = f2bf(b.w);
  *(u16x8*)&dst[i] = o;
}

// ---- gate/up interleaved convert: dst row r of group t: r<128 -> wg, else wu ----
__global__ __launch_bounds__(256) void k_conv_gu(const float* __restrict__ g,
                                                 const float* __restrict__ u,
                                                 unsigned short* __restrict__ dst) {
  int i = blockIdx.x * 256 + threadIdx.x;
  int row = i >> 8;
  int c8 = (i & 255) * 8;
  int t = row >> 8, r = row & 255;
  const float* src = (r < 128) ? (g + (size_t)(t * 128 + r) * DM + c8)
                               : (u + (size_t)(t * 128 + (r - 128)) * DM + c8);
  float4 a = *(const float4*)src;
  float4 b = *(const float4*)(src + 4);
  u16x8 o;
  o[0] = f2bf(a.x); o[1] = f2bf(a.y); o[2] = f2bf(a.z); o[3] = f2bf(a.w);
  o[4] = f2bf(b.x); o[5] = f2bf(b.y); o[6] = f2bf(b.z); o[7] = f2bf(b.w);
  *(u16x8*)&dst[(size_t)row * DM + c8] = o;
}

// ---------------- RMSNorm: one block per row (D=2048, 8 f32/thread) ----------------
__global__ __launch_bounds__(256) void k_rmsnorm(const float* __restrict__ x,
                                                 const float* __restrict__ g,
                                                 unsigned short* __restrict__ out) {
  int row = blockIdx.x, tid = threadIdx.x;
  const float* xr = x + (size_t)row * DM;
  float4 a = *(const float4*)&xr[tid * 8];
  float4 b = *(const float4*)&xr[tid * 8 + 4];
  float ss = a.x * a.x + a.y * a.y + a.z * a.z + a.w * a.w +
             b.x * b.x + b.y * b.y + b.z * b.z + b.w * b.w;
#pragma unroll
  for (int off = 32; off > 0; off >>= 1) ss += __shfl_xor(ss, off, 64);
  __shared__ float red[4];
  if ((tid & 63) == 0) red[tid >> 6] = ss;
  __syncthreads();
  float rs = rsqrtf((red[0] + red[1] + red[2] + red[3]) * (1.0f / DM) + 1e-5f);
  float4 ga = *(const float4*)&g[tid * 8];
  float4 gb = *(const float4*)&g[tid * 8 + 4];
  u16x8 o;
  o[0] = f2bf(a.x * rs * ga.x); o[1] = f2bf(a.y * rs * ga.y);
  o[2] = f2bf(a.z * rs * ga.z); o[3] = f2bf(a.w * rs * ga.w);
  o[4] = f2bf(b.x * rs * gb.x); o[5] = f2bf(b.y * rs * gb.y);
  o[6] = f2bf(b.z * rs * gb.z); o[7] = f2bf(b.w * rs * gb.w);
  *(u16x8*)&out[(size_t)row * DM + tid * 8] = o;
}

// ---------------- RoPE in-place on qkv buffer (q cols 0..2047, k cols 2048..3071) ----
__global__ __launch_bounds__(256) void k_rope(unsigned short* __restrict__ qkv,
                                              const float* __restrict__ cosT,
                                              const float* __restrict__ sinT) {
  int idx = blockIdx.x * 256 + threadIdx.x;
  int j = idx & 63;
  int hh = (idx >> 6) % 24;
  int tok = idx / (64 * 24);
  int s = tok & (SEQ - 1);
  int colbase = (hh < 16) ? hh * HD : DM + (hh - 16) * HD;
  unsigned short* p = qkv + (size_t)tok * 4096 + colbase;
  float lo = bf2f(p[j]), hi = bf2f(p[j + 64]);
  const float* cr = cosT + (size_t)s * HD;
  const float* sr = sinT + (size_t)s * HD;
  float nl = lo * cr[j] - hi * sr[j];
  float nh = hi * cr[j + 64] + lo * sr[j + 64];
  if (hh < 16) { nl *= QK_SCALE_L2E; nh *= QK_SCALE_L2E; }  // fold scale*log2e into q
  p[j] = f2bf(nl);
  p[j + 64] = f2bf(nh);
}

// ---------------- deep-pipelined GEMM: C[M,N] = A[M,K] * Bt[N,K]^T --------------------
// BM=256, BK=32, 8 waves (2Mx4N). Swizzle (r4): 16B-granule g' = g ^ ((row>>1)&3),
// source pre-swizzled (rule #21), conflict-free reads.
// PIPE=0 (r5): 4 LDS buffers (depth-3 counted vmcnt, 4 barriers/K-tile). For 1-block/CU
//   grids (wo/down @256 blocks) where counted depth hides the HBM drain.
// PIPE=1 (r7): 2 LDS buffers (64KB -> 2 blocks/CU), minimal T3 loop: stage(t+1) ->
//   ds_read all frags -> MFMA cluster -> vmcnt(0) -> ONE barrier. Drain covered by the
//   co-resident block (needs grid > 256: gateup 688, qkv 512 via BN=128).
template <int BN, int EPI, int PIPE>
__global__ __launch_bounds__(512, 2) void k_gemm8(
    const unsigned short* __restrict__ A, const unsigned short* __restrict__ Bt,
    unsigned short* __restrict__ outB, float* __restrict__ outF,
    const float* __restrict__ res, int N, int K) {
  constexpr int NF = BN / 64;
  constexpr int BSTMT = BN / 128;
  constexpr int ABY = 256 * 64;
  constexpr int BBY = BN * 64;
  constexpr int BUF = ABY + BBY;
  constexpr int VPK = 2 + BSTMT;
  constexpr int NBUF = PIPE ? 2 : 4;
  __shared__ __attribute__((aligned(16))) unsigned char smem[NBUF * BUF];

  const int tid = threadIdx.x, w = tid >> 6, l = tid & 63;
  const int wr = w >> 2, wc = w & 3, lr = l & 15, lg = l >> 4;
  const int nwg = gridDim.x, bid = blockIdx.x;
  const int bswz = (bid & 7) * (nwg >> 3) + (bid >> 3);
  const int mt = bswz & 15, nt = bswz >> 4;
  const int m0 = mt * 256, n0 = nt * BN;
  const int nk = K >> 5;

  const int srow = w * 16 + (l >> 2);
  const int sg8 = ((l & 3) ^ ((l >> 3) & 3)) * 8;   // pre-swizzle: g ^ ((row>>1)&3)
  const unsigned short* Asrc = A + (size_t)(m0 + srow) * K + sg8;
  const unsigned short* Bsrc = Bt + (size_t)(n0 + srow) * K + sg8;
  const int aoff = (wr * 128 + lr) * 64 + ((lg ^ ((lr >> 1) & 3)) << 4);
  const int boff = (wc * (BN / 4) + lr) * 64 + ((lg ^ ((lr >> 1) & 3)) << 4);

  auto stageA = [&](int kt) {
    unsigned char* bb = smem + (kt & (NBUF - 1)) * BUF;
#pragma unroll
    for (int i = 0; i < 2; i++)
      GLDS16(Asrc + (size_t)i * 128 * K + kt * 32, bb + (i * 512 + w * 64) * 16);
  };
  auto stageB = [&](int kt) {
    unsigned char* bb = smem + (kt & (NBUF - 1)) * BUF + ABY;
#pragma unroll
    for (int i = 0; i < BSTMT; i++)
      GLDS16(Bsrc + (size_t)i * 128 * K + kt * 32, bb + (i * 512 + w * 64) * 16);
  };

  f32x4 acc[8][NF] = {};

  if constexpr (PIPE == 1) {
    // ---- minimal T3 loop: 1 barrier + 1 vmcnt(0) per K-tile, 2 buffers ----
    stageA(0); stageB(0);
    asm volatile("s_waitcnt vmcnt(0)" ::: "memory");
    __builtin_amdgcn_s_barrier();
    for (int kt = 0; kt < nk; kt++) {
      unsigned char* ba = smem + (kt & 1) * BUF;
      unsigned char* bb = ba + ABY;
      if (kt + 1 < nk) { stageA(kt + 1); stageB(kt + 1); }   // buf^1: disjoint
      bf16x8 am[8], bnf[NF];
#pragma unroll
      for (int m = 0; m < 8; m++) am[m] = *(const bf16x8*)(ba + aoff + m * 1024);
#pragma unroll
      for (int n = 0; n < NF; n++) bnf[n] = *(const bf16x8*)(bb + boff + n * 1024);
      __builtin_amdgcn_s_setprio(1);
#pragma unroll
      for (int m = 0; m < 8; m++)
#pragma unroll
        for (int n = 0; n < NF; n++)
          acc[m][n] = __builtin_amdgcn_mfma_f32_16x16x32_bf16(am[m], bnf[n], acc[m][n], 0, 0, 0);
      __builtin_amdgcn_s_setprio(0);
      asm volatile("s_waitcnt vmcnt(0)" ::: "memory");        // stage(t+1) landed
      __builtin_amdgcn_s_barrier();                           // publish t+1, protect t
    }
  } else {
    // ---- r5 counted-vmcnt depth-3 loop, 4 buffers ----
    for (int kt = 0; kt < 3; kt++) { stageA(kt); stageB(kt); }
    asm volatile("s_waitcnt vmcnt(%0)" ::"i"(2 * VPK) : "memory");
    __builtin_amdgcn_s_barrier();
    for (int kt = 0; kt < nk; kt++) {
      unsigned char* ba = smem + (kt & 3) * BUF;
      unsigned char* bb = ba + ABY;
      const bool st = (kt + 3) < nk;
      bf16x8 am[8], bnf[NF];
#pragma unroll
      for (int m = 0; m < 8; m++) am[m] = *(const bf16x8*)(ba + aoff + m * 1024);
#pragma unroll
      for (int n = 0; n < NF; n++) bnf[n] = *(const bf16x8*)(bb + boff + n * 1024);
      if (st) { stageA(kt + 3); stageB(kt + 3); }
      __builtin_amdgcn_s_barrier();
      __builtin_amdgcn_s_setprio(1);
#pragma unroll
      for (int m = 0; m < 8; m++)
#pragma unroll
        for (int n = 0; n < NF; n++)
          acc[m][n] = __builtin_amdgcn_mfma_f32_16x16x32_bf16(am[m], bnf[n], acc[m][n], 0, 0, 0);
      __builtin_amdgcn_s_setprio(0);
      if (kt <= nk - 4)      asm volatile("s_waitcnt vmcnt(%0)" ::"i"(2 * VPK) : "memory");
      else if (kt == nk - 3) asm volatile("s_waitcnt vmcnt(%0)" ::"i"(VPK) : "memory");
      else if (kt == nk - 2) asm volatile("s_waitcnt vmcnt(0)" ::: "memory");
      __builtin_amdgcn_s_barrier();
    }
  }

  const int rbase = wr * 128 + lg * 4;
  const int cbase = wc * (BN / 4) + lr;
  if constexpr (EPI == 0) {
#pragma unroll
    for (int m = 0; m < 8; m++)
#pragma unroll
      for (int n = 0; n < NF; n++)
#pragma unroll
        for (int j = 0; j < 4; j++)
          outB[(size_t)(m0 + rbase + m * 16 + j) * N + n0 + cbase + n * 16] =
              f2bf(acc[m][n][j]);
  } else if constexpr (EPI == 1) {
#pragma unroll
    for (int m = 0; m < 8; m++)
#pragma unroll
      for (int n = 0; n < NF; n++)
#pragma unroll
        for (int j = 0; j < 4; j++) {
          size_t o = (size_t)(m0 + rbase + m * 16 + j) * N + n0 + cbase + n * 16;
          outF[o] = res[o] + acc[m][n][j];
        }
  } else {
    // gateup epilogue, 64KB scratch (two 128-row halves; r6-verified).
    float* gl = (float*)smem;            // [128][128] f32
    const int ab = n0 >> 1;
    __syncthreads();                     // loop's LDS fully consumed
#pragma unroll
    for (int half = 0; half < 2; half++) {
      if (wr == half && wc < 2) {
#pragma unroll
        for (int m = 0; m < 8; m++)
#pragma unroll
          for (int n = 0; n < NF; n++)
#pragma unroll
            for (int j = 0; j < 4; j++)
              gl[(m * 16 + lg * 4 + j) * 128 + wc * 64 + n * 16 + lr] = acc[m][n][j];
      }
      __syncthreads();
      if (wr == half && wc >= 2) {
#pragma unroll
        for (int m = 0; m < 8; m++)
#pragma unroll
          for (int n = 0; n < NF; n++)
#pragma unroll
            for (int j = 0; j < 4; j++) {
              int rl = m * 16 + lg * 4 + j;
              int cl = (wc - 2) * 64 + n * 16 + lr;
              float g = gl[rl * 128 + cl];
              float s = g / (1.0f + __expf(-g));
              outB[(size_t)(m0 + half * 128 + rl) * FF_ + ab + cl] = f2bf(s * acc[m][n][j]);
            }
      }
      __syncthreads();
    }
  }
}

// ---------------- causal GQA flash attention, 32x32 swapped-QK structure --------------
__global__ __launch_bounds__(256) void k_attn2(const unsigned short* __restrict__ qkv,
                                               unsigned short* __restrict__ out) {
  __shared__ __attribute__((aligned(16))) unsigned short lK[2][64 * 128];
  __shared__ __attribute__((aligned(16))) unsigned short lV[2][128 * 64];
  const float NEG = -3.0e38f;
  int bx = blockIdx.x;
  int qtile = 15 - (bx >> 5);          // heaviest q-tiles dispatched first
  int hb = bx & 31;
  int h = hb & 15, b = hb >> 4;
  int q0 = qtile * 128;
  int tid = threadIdx.x, w = tid >> 6, l = tid & 63;
  int l31 = l & 31, half2 = l >> 5;
  const unsigned short* base = qkv + (size_t)b * SEQ * 4096;
  const unsigned short* Kp = base + 2048 + (h >> 1) * HD;
  const unsigned short* Vp = base + 3072 + (h >> 1) * HD;
  const int qw = q0 + w * 32;

  bf16x8 qf[8];
  {
    const unsigned short* qrow = base + (size_t)(qw + l31) * 4096 + h * HD + half2 * 8;
#pragma unroll
    for (int d = 0; d < 8; d++) qf[d] = *(const bf16x8*)(qrow + d * 16);
  }

  f32x16 oacc[4] = {};
  float mrow = NEG, lsum = 0.0f;

  const int vp = tid & 31, vdc = tid >> 5;
  u16x8 va0, va1, vb0, vb1;

  auto stageK = [&](int t) {
    unsigned char* dst = (unsigned char*)lK[t & 1];
#pragma unroll
    for (int i = 0; i < 4; i++) {
      int c = i * 256 + tid;
      int row = c >> 4;
      int g = (c & 15) ^ (row & 7);
      GLDS16(Kp + (size_t)(t * 64 + row) * 4096 + g * 8, dst + (i * 256 + w * 64) * 16);
    }
  };
  auto loadV = [&](int t) {
    const unsigned short* vr = Vp + (size_t)(t * 64 + vp * 2) * 4096 + vdc * 16;
    va0 = *(const u16x8*)(vr);
    va1 = *(const u16x8*)(vr + 8);
    vb0 = *(const u16x8*)(vr + 4096);
    vb1 = *(const u16x8*)(vr + 4096 + 8);
  };

  const int nt = (q0 >> 6) + 2;
  stageK(0);
  loadV(0);

  for (int t = 0; t < nt; t++) {
    __syncthreads();
    {
      unsigned char* lv = (unsigned char*)lV[t & 1];
#pragma unroll
      for (int j = 0; j < 16; j++) {
        int dd = vdc * 16 + j;
        unsigned short lo = (j < 8) ? va0[j] : va1[j - 8];
        unsigned short hi = (j < 8) ? vb0[j] : vb1[j - 8];
        unsigned int pkv = (unsigned int)lo | ((unsigned int)hi << 16);
        *(unsigned int*)(lv + dd * 128 + (((vp >> 2) ^ (dd & 7)) * 16) + (vp & 3) * 4) = pkv;
      }
    }
    __syncthreads();
    if (t + 1 < nt) { stageK(t + 1); loadV(t + 1); }
    const int kv0 = t * 64;
    if (kv0 <= qw + 31) {
      f32x16 sc[2] = {};
      const unsigned char* lk = (const unsigned char*)lK[t & 1];
#pragma unroll
      for (int hh = 0; hh < 2; hh++) {
        int kk = hh * 32 + l31;
        const unsigned char* krow = lk + kk * 256;
#pragma unroll
        for (int d = 0; d < 8; d++) {
          bf16x8 kf = *(const bf16x8*)(krow + (((d * 2 + half2) ^ (kk & 7)) * 16));
          sc[hh] = __builtin_amdgcn_mfma_f32_32x32x16_bf16(kf, qf[d], sc[hh], 0, 0, 0);
        }
      }
      const int qa = qw + l31;
      if (kv0 + 63 > qw) {
#pragma unroll
        for (int hh = 0; hh < 2; hh++)
#pragma unroll
          for (int r = 0; r < 16; r++) {
            int kva = kv0 + hh * 32 + (r & 3) + 8 * (r >> 2) + 4 * half2;
            if (kva > qa) sc[hh][r] = NEG;
          }
      }
      float mx = sc[0][0];
#pragma unroll
      for (int r = 1; r < 16; r++) mx = fmaxf(mx, sc[0][r]);
#pragma unroll
      for (int r = 0; r < 16; r++) mx = fmaxf(mx, sc[1][r]);
      mx = fmaxf(mx, __shfl_xor(mx, 32));
      bool ok = (mx <= mrow + 11.0f);
      if (__ballot(ok) != ~0ull) {
        float mnew = fmaxf(mrow, mx);
        float fct = fexp2(mrow - mnew);
        mrow = mnew;
        lsum *= fct;
#pragma unroll
        for (int r = 0; r < 16; r++) {
          int rr = (r & 3) + 8 * (r >> 2) + 4 * half2;
          float fr = __shfl(fct, rr);
#pragma unroll
          for (int d = 0; d < 4; d++) oacc[d][r] *= fr;
        }
      }
      float ps = 0.0f;
#pragma unroll
      for (int hh = 0; hh < 2; hh++)
#pragma unroll
        for (int r = 0; r < 16; r++) {
          float e = fexp2(sc[hh][r] - mrow);
          sc[hh][r] = e;
          ps += e;
        }
      ps += __shfl_xor(ps, 32);
      lsum += ps;
      const unsigned char* lv = (const unsigned char*)lV[t & 1];
#pragma unroll
      for (int s = 0; s < 4; s++) {
        const int hh = s >> 1;
        const int r0 = (s & 1) * 8;
        unsigned int lo0, lo1, hi0, hi1;
        if (hh == 0) {
          lo0 = pk2(sc[0][r0 + 0], sc[0][r0 + 1]); lo1 = pk2(sc[0][r0 + 2], sc[0][r0 + 3]);
          hi0 = pk2(sc[0][r0 + 4], sc[0][r0 + 5]); hi1 = pk2(sc[0][r0 + 6], sc[0][r0 + 7]);
        } else {
          lo0 = pk2(sc[1][r0 + 0], sc[1][r0 + 1]); lo1 = pk2(sc[1][r0 + 2], sc[1][r0 + 3]);
          hi0 = pk2(sc[1][r0 + 4], sc[1][r0 + 5]); hi1 = pk2(sc[1][r0 + 6], sc[1][r0 + 7]);
        }
        unsigned int s0 = half2 ? lo0 : hi0, s1 = half2 ? lo1 : hi1;
        unsigned int rc0 = (unsigned int)__shfl_xor((int)s0, 32);
        unsigned int rc1 = (unsigned int)__shfl_xor((int)s1, 32);
        u32x4 fr;
        fr[0] = half2 ? rc0 : lo0; fr[1] = half2 ? rc1 : lo1;
        fr[2] = half2 ? hi0 : rc0; fr[3] = half2 ? hi1 : rc1;
        bf16x8 pa = __builtin_bit_cast(bf16x8, fr);
#pragma unroll
        for (int d = 0; d < 4; d++) {
          int dd = d * 32 + l31;
          bf16x8 vf = *(const bf16x8*)(lv + dd * 128 + (((s * 2 + half2) ^ (dd & 7)) * 16));
          oacc[d] = __builtin_amdgcn_mfma_f32_32x32x16_bf16(pa, vf, oacc[d], 0, 0, 0);
        }
      }
    }
  }
  float inv = 1.0f / lsum;
#pragma unroll
  for (int r = 0; r < 16; r++) {
    int rr = (r & 3) + 8 * (r >> 2) + 4 * half2;
    float ir = __shfl(inv, rr);
    size_t ob = ((size_t)(b * SEQ + qw + rr)) * 2048 + h * HD;
#pragma unroll
    for (int d = 0; d < 4; d++)
      out[ob + d * 32 + l31] = f2bf(oacc[d][r] * ir);
  }
}

// ---------------- launcher -------------------------------------------------------------
extern "C" void kernel_launch(void* const* d_in, const int* in_sizes, int n_in,
                              void* d_out, int out_size, void* d_ws, size_t ws_size,
                              hipStream_t stream) {
  const float* x = (const float*)d_in[0];
  const float* cosT = (const float*)d_in[1];
  const float* sinT = (const float*)d_in[2];
  const float* wq = (const float*)d_in[3];
  const float* wk = (const float*)d_in[4];
  const float* wv = (const float*)d_in[5];
  const float* wo = (const float*)d_in[6];
  const float* wg = (const float*)d_in[7];
  const float* wu = (const float*)d_in[8];
  const float* wd = (const float*)d_in[9];
  const float* g1 = (const float*)d_in[10];
  const float* g2 = (const float*)d_in[11];
  float* out = (float*)d_out;
  char* ws = (char*)d_ws;

  unsigned short* wqkv = (unsigned short*)(ws + 0);
  unsigned short* hbuf = (unsigned short*)(ws + 16777216);
  unsigned short* qkv = (unsigned short*)(ws + 33554432);
  unsigned short* attn_o = (unsigned short*)(ws + 67108864);
  unsigned short* wo_bf = (unsigned short*)(ws + 83886080);
  unsigned short* wgu = (unsigned short*)(ws + 33554432);
  unsigned short* act = (unsigned short*)(ws + 92274688);
  unsigned short* wdown = (unsigned short*)(ws + 0);

  // ---- attention sub-block ----
  k_conv<<<2048, 256, 0, stream>>>(wq, wqkv);
  k_conv<<<1024, 256, 0, stream>>>(wk, wqkv + 4194304);
  k_conv<<<1024, 256, 0, stream>>>(wv, wqkv + 6291456);
  k_rmsnorm<<<4096, 256, 0, stream>>>(x, g1, hbuf);
  k_gemm8<128, 0, 1><<<512, 512, 0, stream>>>(hbuf, wqkv, qkv, nullptr, nullptr,
                                              4096, 2048);
  k_rope<<<24576, 256, 0, stream>>>(qkv, cosT, sinT);
  k_attn2<<<512, 256, 0, stream>>>(qkv, attn_o);
  k_conv<<<2048, 256, 0, stream>>>(wo, wo_bf);
  k_gemm8<128, 1, 0><<<256, 512, 0, stream>>>(attn_o, wo_bf, nullptr, out, x,
                                              2048, 2048);
  // ---- SwiGLU MLP sub-block ----
  k_rmsnorm<<<4096, 256, 0, stream>>>(out, g2, hbuf);
  k_conv_gu<<<11008, 256, 0, stream>>>(wg, wu, wgu);
  k_gemm8<256, 2, 1><<<688, 512, 0, stream>>>(hbuf, wgu, act, nullptr, nullptr,
                                              11008, 2048);
  k_conv<<<5504, 256, 0, stream>>>(wd, wdown);
  k_gemm8<128, 1, 0><<<256, 512, 0, stream>>>(act, wdown, nullptr, out, out,
                                              2048, 5504);
}

// Round 8
// 595.710 us; speedup vs baseline: 1.1606x; 1.0463x over previous
//
#include <hip/hip_runtime.h>

// LLM block: B=2,S=2048,D=2048,H=16,KVH=8,HD=128,FF=5504, f32 in/out, bf16 MFMA compute.
// Workspace layout (bytes), peak ~137MB:
//   wqkv_bf16   [4096,2048]  @ 0
//   h/h2_bf16   [4096,2048]  @ 16777216
//   qkv_bf16    [4096,4096]  @ 33554432   (region reused later by wgu)
//   attn_out    [4096,2048]  @ 67108864
//   wo_bf16     [2048,2048]  @ 83886080
//   wgu_bf16    [11008,2048] @ 33554432   (interleaved: per 256-row group = 128 gate | 128 up)
//   act_bf16    [4096,5504]  @ 92274688
//   wdown_bf16  [2048,5504]  @ 0
//   x1 (f32 residual) lives in d_out.

#define DM 2048
#define SEQ 2048
#define HD 128
#define FF_ 5504
// 1/sqrt(128) * log2(e): attention runs softmax in exp2 domain.
#define QK_SCALE_L2E 0.12751744f

typedef __bf16 bf16x8 __attribute__((ext_vector_type(8)));
typedef float f32x4 __attribute__((ext_vector_type(4)));
typedef float f32x16 __attribute__((ext_vector_type(16)));
typedef unsigned short u16x8 __attribute__((ext_vector_type(8)));
typedef unsigned int u32x4 __attribute__((ext_vector_type(4)));

typedef __attribute__((address_space(1))) void* gas1;
typedef __attribute__((address_space(3))) void* las3;
#define GLDS16(g, s) __builtin_amdgcn_global_load_lds((gas1)(g), (las3)(s), 16, 0, 0)

static __device__ __forceinline__ float bf2f(unsigned short u) {
  union { unsigned int i; float f; } c; c.i = ((unsigned int)u) << 16; return c.f;
}
static __device__ __forceinline__ unsigned short f2bf(float f) {
  __bf16 b = (__bf16)f;
  return __builtin_bit_cast(unsigned short, b);
}
static __device__ __forceinline__ unsigned int pk2(float a, float b) {
  return (unsigned int)f2bf(a) | ((unsigned int)f2bf(b) << 16);
}
// native exp2 (v_exp_f32); __exp2f doesn't exist in HIP headers (r3 compile fail)
static __device__ __forceinline__ float fexp2(float x) { return exp2f(x); }

// ---------------- f32 -> bf16 convert (8 elems/thread, exact grid) ----------------
__global__ __launch_bounds__(256) void k_conv(const float* __restrict__ src,
                                              unsigned short* __restrict__ dst) {
  size_t i = (size_t)(blockIdx.x * 256 + threadIdx.x) * 8;
  float4 a = *(const float4*)&src[i];
  float4 b = *(const float4*)&src[i + 4];
  u16x8 o;
  o[0] = f2bf(a.x); o[1] = f2bf(a.y); o[2] = f2bf(a.z); o[3] = f2bf(a.w);
  o[4] = f2bf(b.x); o[5] = f2bf(b.y); o[6] = f2bf(b.z); o[7] = f2bf(b.w);
  *(u16x8*)&dst[i] = o;
}

// ---- gate/up interleaved convert: dst row r of group t: r<128 -> wg, else wu ----
__global__ __launch_bounds__(256) void k_conv_gu(const float* __restrict__ g,
                                                 const float* __restrict__ u,
                                                 unsigned short* __restrict__ dst) {
  int i = blockIdx.x * 256 + threadIdx.x;
  int row = i >> 8;
  int c8 = (i & 255) * 8;
  int t = row >> 8, r = row & 255;
  const float* src = (r < 128) ? (g + (size_t)(t * 128 + r) * DM + c8)
                               : (u + (size_t)(t * 128 + (r - 128)) * DM + c8);
  float4 a = *(const float4*)src;
  float4 b = *(const float4*)(src + 4);
  u16x8 o;
  o[0] = f2bf(a.x); o[1] = f2bf(a.y); o[2] = f2bf(a.z); o[3] = f2bf(a.w);
  o[4] = f2bf(b.x); o[5] = f2bf(b.y); o[6] = f2bf(b.z); o[7] = f2bf(b.w);
  *(u16x8*)&dst[(size_t)row * DM + c8] = o;
}

// ---------------- RMSNorm: one block per row (D=2048, 8 f32/thread) ----------------
__global__ __launch_bounds__(256) void k_rmsnorm(const float* __restrict__ x,
                                                 const float* __restrict__ g,
                                                 unsigned short* __restrict__ out) {
  int row = blockIdx.x, tid = threadIdx.x;
  const float* xr = x + (size_t)row * DM;
  float4 a = *(const float4*)&xr[tid * 8];
  float4 b = *(const float4*)&xr[tid * 8 + 4];
  float ss = a.x * a.x + a.y * a.y + a.z * a.z + a.w * a.w +
             b.x * b.x + b.y * b.y + b.z * b.z + b.w * b.w;
#pragma unroll
  for (int off = 32; off > 0; off >>= 1) ss += __shfl_xor(ss, off, 64);
  __shared__ float red[4];
  if ((tid & 63) == 0) red[tid >> 6] = ss;
  __syncthreads();
  float rs = rsqrtf((red[0] + red[1] + red[2] + red[3]) * (1.0f / DM) + 1e-5f);
  float4 ga = *(const float4*)&g[tid * 8];
  float4 gb = *(const float4*)&g[tid * 8 + 4];
  u16x8 o;
  o[0] = f2bf(a.x * rs * ga.x); o[1] = f2bf(a.y * rs * ga.y);
  o[2] = f2bf(a.z * rs * ga.z); o[3] = f2bf(a.w * rs * ga.w);
  o[4] = f2bf(b.x * rs * gb.x); o[5] = f2bf(b.y * rs * gb.y);
  o[6] = f2bf(b.z * rs * gb.z); o[7] = f2bf(b.w * rs * gb.w);
  *(u16x8*)&out[(size_t)row * DM + tid * 8] = o;
}

// ---------------- RoPE in-place on qkv buffer (q cols 0..2047, k cols 2048..3071) ----
__global__ __launch_bounds__(256) void k_rope(unsigned short* __restrict__ qkv,
                                              const float* __restrict__ cosT,
                                              const float* __restrict__ sinT) {
  int idx = blockIdx.x * 256 + threadIdx.x;
  int j = idx & 63;
  int hh = (idx >> 6) % 24;
  int tok = idx / (64 * 24);
  int s = tok & (SEQ - 1);
  int colbase = (hh < 16) ? hh * HD : DM + (hh - 16) * HD;
  unsigned short* p = qkv + (size_t)tok * 4096 + colbase;
  float lo = bf2f(p[j]), hi = bf2f(p[j + 64]);
  const float* cr = cosT + (size_t)s * HD;
  const float* sr = sinT + (size_t)s * HD;
  float nl = lo * cr[j] - hi * sr[j];
  float nh = hi * cr[j + 64] + lo * sr[j + 64];
  if (hh < 16) { nl *= QK_SCALE_L2E; nh *= QK_SCALE_L2E; }  // fold scale*log2e into q
  p[j] = f2bf(nl);
  p[j + 64] = f2bf(nh);
}

// ================= 8-phase GEMM (m201 port): C[M,N] = A[M,K]*Bt[N,K]^T ================
// BM=BN=256, BK=64, 512 thr (8 waves 2Mx4N), LDS 2 x 64KB (per-K-tile dbuf).
// Buffer layout: [Ah0' 16K][Ah1' 16K][Bh0' 16K][Bh1' 16K], halves reorganized by USE:
//   Ah0' = m-frags 0-3 rows of both wr ({0-63}u{128-191}); Ah1' = m4-7 rows.
//   Bh0' = n-frags 0-1 rows of all wc; Bh1' = n2-3 rows.
// Per K-tile, 4 phases: ph1 {dsr A m0-3 + B n0-1; stage Ah0'(kt+1); MFMA Q(m0-3,n0-1)},
//   ph2 {dsr B n2-3; stage Bh0'; Q(m0-3,n2-3)}, ph3 {dsr A m4-7; stage Bh1';
//   Q(m4-7,n2-3)}, ph4 {stage Ah1'; Q(m4-7,n0-1)}. Each staged half-tile's first use
//   is >=3 phases after issue. FIFO window -> vmcnt(4) at end of ph1/ph2/ph4 (tail 2/0).
// Swizzle: granule(16B) ^= (row&7) (128B rows: bank = 4*granule mod 32, row cancels);
//   source pre-swizzled, GLDS dest linear (rule #21).
template <int EPI>
__global__ __launch_bounds__(512, 1) void k_gemm8p(
    const unsigned short* __restrict__ A, const unsigned short* __restrict__ Bt,
    unsigned short* __restrict__ outB, float* __restrict__ outF,
    const float* __restrict__ res, int N, int K) {
  __shared__ __attribute__((aligned(16))) unsigned char smem[2][65536];
  const int tid = threadIdx.x, w = tid >> 6, l = tid & 63;
  const int wr = w >> 2, wc = w & 3, lr = l & 15, lg = l >> 4;
  const int nwg = gridDim.x, bid = blockIdx.x;
  const int bswz = (bid & 7) * (nwg >> 3) + (bid >> 3);   // XCD swizzle (nwg%8==0)
  const int mt = bswz & 15, nt = bswz >> 4;
  const int m0 = mt * 256, n0 = nt * 256;
  const int nkt = K >> 6;

  // stage addressing: GLDS i covers local rows i*64+(tid>>3), chunk tid&7 (pre-swz)
  const int rA0 = tid >> 3;                               // A local row (i=0)
  const int rB0 = ((tid >> 8) << 6) + ((tid >> 3) & 31);  // B base row within reorg
  const int sc = ((tid & 7) ^ ((tid >> 3) & 7)) * 8;      // src col elems, pre-swizzled
  const unsigned short* Abase = A + (size_t)(m0 + rA0) * K + sc;
  const unsigned short* Bbase = Bt + (size_t)(n0 + rB0) * K + sc;

  auto stA = [&](int kt, int h) {   // stage A half h' of K-tile kt
    unsigned char* dst = smem[kt & 1] + h * 16384;
    const unsigned short* s = Abase + (size_t)(h * 64) * K + kt * 64;
    GLDS16(s, dst + tid * 16);
    GLDS16(s + (size_t)128 * K, dst + (512 + tid) * 16);
  };
  auto stB = [&](int kt, int h) {   // stage B half h' of K-tile kt
    unsigned char* dst = smem[kt & 1] + 32768 + h * 16384;
    const unsigned short* s = Bbase + (size_t)(h * 32) * K + kt * 64;
    GLDS16(s, dst + tid * 16);
    GLDS16(s + (size_t)128 * K, dst + (512 + tid) * 16);
  };

  const int aRow = (wr * 64 + lr) * 128;
  const int bRow = (wc * 32 + lr) * 128;
  const int axr = lr & 7;
#define RDA(BUF, M, KK)                                                        \
  (*(const bf16x8*)((BUF) + ((M) >> 2) * 16384 + aRow + ((M) & 3) * 2048 +     \
                    ((((KK) * 4 + lg) ^ axr) << 4)))
#define RDB(BUF, NN, KK)                                                       \
  (*(const bf16x8*)((BUF) + 32768 + ((NN) >> 1) * 16384 + bRow +               \
                    ((NN) & 1) * 2048 + ((((KK) * 4 + lg) ^ axr) << 4)))

  f32x4 acc[8][4] = {};
  bf16x8 aq[4][2], bq0[2][2], bq1[2][2];

  // prologue: K-tile 0's four half-tiles in steady-state FIFO order
  stA(0, 0); stB(0, 0); stB(0, 1); stA(0, 1);
  asm volatile("s_waitcnt vmcnt(4)" ::: "memory");   // Ah0',Bh0' landed
  __builtin_amdgcn_s_barrier();

#define MMQ(MB, NB, BQ)                                                        \
  _Pragma("unroll") for (int m = 0; m < 4; m++)                                \
    _Pragma("unroll") for (int n = 0; n < 2; n++)                              \
      _Pragma("unroll") for (int kk = 0; kk < 2; kk++)                         \
          acc[(MB) + m][(NB) + n] = __builtin_amdgcn_mfma_f32_16x16x32_bf16(   \
              aq[m][kk], BQ[n][kk], acc[(MB) + m][(NB) + n], 0, 0, 0);

#define KT8(KT, ST, W1, W2, HASW4)                                             \
  {                                                                            \
    const unsigned char* buf = smem[(KT) & 1];                                 \
    /* ---- phase 1 ---- */                                                    \
    _Pragma("unroll") for (int m = 0; m < 4; m++)                              \
      _Pragma("unroll") for (int kk = 0; kk < 2; kk++)                         \
          aq[m][kk] = RDA(buf, m, kk);                                         \
    _Pragma("unroll") for (int n = 0; n < 2; n++)                              \
      _Pragma("unroll") for (int kk = 0; kk < 2; kk++)                         \
          bq0[n][kk] = RDB(buf, n, kk);                                        \
    if (ST) stA((KT) + 1, 0);                                                  \
    __builtin_amdgcn_s_barrier();                                              \
    asm volatile("s_waitcnt lgkmcnt(0)" ::: "memory");                         \
    __builtin_amdgcn_sched_barrier(0);                                         \
    __builtin_amdgcn_s_setprio(1);                                             \
    MMQ(0, 0, bq0)                                                             \
    __builtin_amdgcn_s_setprio(0);                                             \
    asm volatile("s_waitcnt vmcnt(%0)" ::"i"(W1) : "memory");                  \
    __builtin_amdgcn_s_barrier();                                              \
    /* ---- phase 2 ---- */                                                    \
    _Pragma("unroll") for (int n = 0; n < 2; n++)                              \
      _Pragma("unroll") for (int kk = 0; kk < 2; kk++)                         \
          bq1[n][kk] = RDB(buf, n + 2, kk);                                    \
    if (ST) stB((KT) + 1, 0);                                                  \
    __builtin_amdgcn_s_barrier();                                              \
    asm volatile("s_waitcnt lgkmcnt(0)" ::: "memory");                         \
    __builtin_amdgcn_sched_barrier(0);                                         \
    __builtin_amdgcn_s_setprio(1);                                             \
    MMQ(0, 2, bq1)                                                             \
    __builtin_amdgcn_s_setprio(0);                                             \
    asm volatile("s_waitcnt vmcnt(%0)" ::"i"(W2) : "memory");                  \
    __builtin_amdgcn_s_barrier();                                              \
    /* ---- phase 3 ---- */                                                    \
    _Pragma("unroll") for (int m = 0; m < 4; m++)                              \
      _Pragma("unroll") for (int kk = 0; kk < 2; kk++)                         \
          aq[m][kk] = RDA(buf, m + 4, kk);                                     \
    if (ST) stB((KT) + 1, 1);                                                  \
    __builtin_amdgcn_s_barrier();                                              \
    asm volatile("s_waitcnt lgkmcnt(0)" ::: "memory");                         \
    __builtin_amdgcn_sched_barrier(0);                                         \
    __builtin_amdgcn_s_setprio(1);                                             \
    MMQ(4, 2, bq1)                                                             \
    __builtin_amdgcn_s_setprio(0);                                             \
    __builtin_amdgcn_s_barrier();                                              \
    /* ---- phase 4 ---- */                                                    \
    if (ST) stA((KT) + 1, 1);                                                  \
    __builtin_amdgcn_s_barrier();                                              \
    __builtin_amdgcn_s_setprio(1);                                             \
    MMQ(4, 0, bq0)                                                             \
    __builtin_amdgcn_s_setprio(0);                                             \
    if (HASW4) asm volatile("s_waitcnt vmcnt(4)" ::: "memory");                \
    __builtin_amdgcn_s_barrier();                                              \
  }

  for (int kt = 0; kt < nkt - 1; kt++) KT8(kt, true, 4, 4, true);
  KT8(nkt - 1, false, 2, 0, false);
#undef KT8
#undef MMQ
#undef RDA
#undef RDB

  const int rbase = wr * 128 + lg * 4;
  const int cbase = wc * 64 + lr;
  if constexpr (EPI == 0) {
#pragma unroll
    for (int m = 0; m < 8; m++)
#pragma unroll
      for (int n = 0; n < 4; n++)
#pragma unroll
        for (int j = 0; j < 4; j++)
          outB[(size_t)(m0 + rbase + m * 16 + j) * N + n0 + cbase + n * 16] =
              f2bf(acc[m][n][j]);
  } else if constexpr (EPI == 1) {
#pragma unroll
    for (int m = 0; m < 8; m++)
#pragma unroll
      for (int n = 0; n < 4; n++)
#pragma unroll
        for (int j = 0; j < 4; j++) {
          size_t o = (size_t)(m0 + rbase + m * 16 + j) * N + n0 + cbase + n * 16;
          outF[o] = res[o] + acc[m][n][j];
        }
  } else {
    // gateup: silu(gate)*up via 64KB f32 LDS scratch, two 128-row halves.
    float* gl = (float*)smem;            // [128][128] f32
    const int ab = n0 >> 1;
    __syncthreads();
#pragma unroll
    for (int half = 0; half < 2; half++) {
      if (wr == half && wc < 2) {
#pragma unroll
        for (int m = 0; m < 8; m++)
#pragma unroll
          for (int n = 0; n < 4; n++)
#pragma unroll
            for (int j = 0; j < 4; j++)
              gl[(m * 16 + lg * 4 + j) * 128 + wc * 64 + n * 16 + lr] = acc[m][n][j];
      }
      __syncthreads();
      if (wr == half && wc >= 2) {
#pragma unroll
        for (int m = 0; m < 8; m++)
#pragma unroll
          for (int n = 0; n < 4; n++)
#pragma unroll
            for (int j = 0; j < 4; j++) {
              int rl = m * 16 + lg * 4 + j;
              int cl = (wc - 2) * 64 + n * 16 + lr;
              float g = gl[rl * 128 + cl];
              float s = g / (1.0f + __expf(-g));
              outB[(size_t)(m0 + half * 128 + rl) * FF_ + ab + cl] = f2bf(s * acc[m][n][j]);
            }
      }
      __syncthreads();
    }
  }
}

// ---------------- r5 counted-vmcnt GEMM (BK=32, 4 buffers) for WO / down --------------
template <int BN, int EPI, int PIPE>
__global__ __launch_bounds__(512, 2) void k_gemm8(
    const unsigned short* __restrict__ A, const unsigned short* __restrict__ Bt,
    unsigned short* __restrict__ outB, float* __restrict__ outF,
    const float* __restrict__ res, int N, int K) {
  constexpr int NF = BN / 64;
  constexpr int BSTMT = BN / 128;
  constexpr int ABY = 256 * 64;
  constexpr int BBY = BN * 64;
  constexpr int BUF = ABY + BBY;
  constexpr int VPK = 2 + BSTMT;
  __shared__ __attribute__((aligned(16))) unsigned char smem[4 * BUF];

  const int tid = threadIdx.x, w = tid >> 6, l = tid & 63;
  const int wr = w >> 2, wc = w & 3, lr = l & 15, lg = l >> 4;
  const int nwg = gridDim.x, bid = blockIdx.x;
  const int bswz = (bid & 7) * (nwg >> 3) + (bid >> 3);
  const int mt = bswz & 15, nt = bswz >> 4;
  const int m0 = mt * 256, n0 = nt * BN;
  const int nk = K >> 5;

  const int srow = w * 16 + (l >> 2);
  const int sg8 = ((l & 3) ^ ((l >> 3) & 3)) * 8;   // pre-swizzle: g ^ ((row>>1)&3)
  const unsigned short* Asrc = A + (size_t)(m0 + srow) * K + sg8;
  const unsigned short* Bsrc = Bt + (size_t)(n0 + srow) * K + sg8;
  const int aoff = (wr * 128 + lr) * 64 + ((lg ^ ((lr >> 1) & 3)) << 4);
  const int boff = (wc * (BN / 4) + lr) * 64 + ((lg ^ ((lr >> 1) & 3)) << 4);

  auto stageA = [&](int kt) {
    unsigned char* bb = smem + (kt & 3) * BUF;
#pragma unroll
    for (int i = 0; i < 2; i++)
      GLDS16(Asrc + (size_t)i * 128 * K + kt * 32, bb + (i * 512 + w * 64) * 16);
  };
  auto stageB = [&](int kt) {
    unsigned char* bb = smem + (kt & 3) * BUF + ABY;
#pragma unroll
    for (int i = 0; i < BSTMT; i++)
      GLDS16(Bsrc + (size_t)i * 128 * K + kt * 32, bb + (i * 512 + w * 64) * 16);
  };

  f32x4 acc[8][NF] = {};

  for (int kt = 0; kt < 3; kt++) { stageA(kt); stageB(kt); }
  asm volatile("s_waitcnt vmcnt(%0)" ::"i"(2 * VPK) : "memory");
  __builtin_amdgcn_s_barrier();
  for (int kt = 0; kt < nk; kt++) {
    unsigned char* ba = smem + (kt & 3) * BUF;
    unsigned char* bb = ba + ABY;
    const bool st = (kt + 3) < nk;
    bf16x8 am[8], bnf[NF];
#pragma unroll
    for (int m = 0; m < 8; m++) am[m] = *(const bf16x8*)(ba + aoff + m * 1024);
#pragma unroll
    for (int n = 0; n < NF; n++) bnf[n] = *(const bf16x8*)(bb + boff + n * 1024);
    if (st) { stageA(kt + 3); stageB(kt + 3); }
    __builtin_amdgcn_s_barrier();
    __builtin_amdgcn_s_setprio(1);
#pragma unroll
    for (int m = 0; m < 8; m++)
#pragma unroll
      for (int n = 0; n < NF; n++)
        acc[m][n] = __builtin_amdgcn_mfma_f32_16x16x32_bf16(am[m], bnf[n], acc[m][n], 0, 0, 0);
    __builtin_amdgcn_s_setprio(0);
    if (kt <= nk - 4)      asm volatile("s_waitcnt vmcnt(%0)" ::"i"(2 * VPK) : "memory");
    else if (kt == nk - 3) asm volatile("s_waitcnt vmcnt(%0)" ::"i"(VPK) : "memory");
    else if (kt == nk - 2) asm volatile("s_waitcnt vmcnt(0)" ::: "memory");
    __builtin_amdgcn_s_barrier();
  }

  const int rbase = wr * 128 + lg * 4;
  const int cbase = wc * (BN / 4) + lr;
  if constexpr (EPI == 0) {
#pragma unroll
    for (int m = 0; m < 8; m++)
#pragma unroll
      for (int n = 0; n < NF; n++)
#pragma unroll
        for (int j = 0; j < 4; j++)
          outB[(size_t)(m0 + rbase + m * 16 + j) * N + n0 + cbase + n * 16] =
              f2bf(acc[m][n][j]);
  } else {
#pragma unroll
    for (int m = 0; m < 8; m++)
#pragma unroll
      for (int n = 0; n < NF; n++)
#pragma unroll
        for (int j = 0; j < 4; j++) {
          size_t o = (size_t)(m0 + rbase + m * 16 + j) * N + n0 + cbase + n * 16;
          outF[o] = res[o] + acc[m][n][j];
        }
  }
}

// ---------------- causal GQA flash attention, 32x32 swapped-QK structure --------------
__global__ __launch_bounds__(256) void k_attn2(const unsigned short* __restrict__ qkv,
                                               unsigned short* __restrict__ out) {
  __shared__ __attribute__((aligned(16))) unsigned short lK[2][64 * 128];
  __shared__ __attribute__((aligned(16))) unsigned short lV[2][128 * 64];
  const float NEG = -3.0e38f;
  int bx = blockIdx.x;
  int qtile = 15 - (bx >> 5);          // heaviest q-tiles dispatched first
  int hb = bx & 31;
  int h = hb & 15, b = hb >> 4;
  int q0 = qtile * 128;
  int tid = threadIdx.x, w = tid >> 6, l = tid & 63;
  int l31 = l & 31, half2 = l >> 5;
  const unsigned short* base = qkv + (size_t)b * SEQ * 4096;
  const unsigned short* Kp = base + 2048 + (h >> 1) * HD;
  const unsigned short* Vp = base + 3072 + (h >> 1) * HD;
  const int qw = q0 + w * 32;

  bf16x8 qf[8];
  {
    const unsigned short* qrow = base + (size_t)(qw + l31) * 4096 + h * HD + half2 * 8;
#pragma unroll
    for (int d = 0; d < 8; d++) qf[d] = *(const bf16x8*)(qrow + d * 16);
  }

  f32x16 oacc[4] = {};
  float mrow = NEG, lsum = 0.0f;

  const int vp = tid & 31, vdc = tid >> 5;
  u16x8 va0, va1, vb0, vb1;

  auto stageK = [&](int t) {
    unsigned char* dst = (unsigned char*)lK[t & 1];
#pragma unroll
    for (int i = 0; i < 4; i++) {
      int c = i * 256 + tid;
      int row = c >> 4;
      int g = (c & 15) ^ (row & 7);
      GLDS16(Kp + (size_t)(t * 64 + row) * 4096 + g * 8, dst + (i * 256 + w * 64) * 16);
    }
  };
  auto loadV = [&](int t) {
    const unsigned short* vr = Vp + (size_t)(t * 64 + vp * 2) * 4096 + vdc * 16;
    va0 = *(const u16x8*)(vr);
    va1 = *(const u16x8*)(vr + 8);
    vb0 = *(const u16x8*)(vr + 4096);
    vb1 = *(const u16x8*)(vr + 4096 + 8);
  };

  const int nt = (q0 >> 6) + 2;
  stageK(0);
  loadV(0);

  for (int t = 0; t < nt; t++) {
    __syncthreads();
    {
      unsigned char* lv = (unsigned char*)lV[t & 1];
#pragma unroll
      for (int j = 0; j < 16; j++) {
        int dd = vdc * 16 + j;
        unsigned short lo = (j < 8) ? va0[j] : va1[j - 8];
        unsigned short hi = (j < 8) ? vb0[j] : vb1[j - 8];
        unsigned int pkv = (unsigned int)lo | ((unsigned int)hi << 16);
        *(unsigned int*)(lv + dd * 128 + (((vp >> 2) ^ (dd & 7)) * 16) + (vp & 3) * 4) = pkv;
      }
    }
    __syncthreads();
    if (t + 1 < nt) { stageK(t + 1); loadV(t + 1); }
    const int kv0 = t * 64;
    if (kv0 <= qw + 31) {
      f32x16 sc[2] = {};
      const unsigned char* lk = (const unsigned char*)lK[t & 1];
#pragma unroll
      for (int hh = 0; hh < 2; hh++) {
        int kk = hh * 32 + l31;
        const unsigned char* krow = lk + kk * 256;
#pragma unroll
        for (int d = 0; d < 8; d++) {
          bf16x8 kf = *(const bf16x8*)(krow + (((d * 2 + half2) ^ (kk & 7)) * 16));
          sc[hh] = __builtin_amdgcn_mfma_f32_32x32x16_bf16(kf, qf[d], sc[hh], 0, 0, 0);
        }
      }
      const int qa = qw + l31;
      if (kv0 + 63 > qw) {
#pragma unroll
        for (int hh = 0; hh < 2; hh++)
#pragma unroll
          for (int r = 0; r < 16; r++) {
            int kva = kv0 + hh * 32 + (r & 3) + 8 * (r >> 2) + 4 * half2;
            if (kva > qa) sc[hh][r] = NEG;
          }
      }
      float mx = sc[0][0];
#pragma unroll
      for (int r = 1; r < 16; r++) mx = fmaxf(mx, sc[0][r]);
#pragma unroll
      for (int r = 0; r < 16; r++) mx = fmaxf(mx, sc[1][r]);
      mx = fmaxf(mx, __shfl_xor(mx, 32));
      bool ok = (mx <= mrow + 11.0f);
      if (__ballot(ok) != ~0ull) {
        float mnew = fmaxf(mrow, mx);
        float fct = fexp2(mrow - mnew);
        mrow = mnew;
        lsum *= fct;
#pragma unroll
        for (int r = 0; r < 16; r++) {
          int rr = (r & 3) + 8 * (r >> 2) + 4 * half2;
          float fr = __shfl(fct, rr);
#pragma unroll
          for (int d = 0; d < 4; d++) oacc[d][r] *= fr;
        }
      }
      float ps = 0.0f;
#pragma unroll
      for (int hh = 0; hh < 2; hh++)
#pragma unroll
        for (int r = 0; r < 16; r++) {
          float e = fexp2(sc[hh][r] - mrow);
          sc[hh][r] = e;
          ps += e;
        }
      ps += __shfl_xor(ps, 32);
      lsum += ps;
      const unsigned char* lv = (const unsigned char*)lV[t & 1];
#pragma unroll
      for (int s = 0; s < 4; s++) {
        const int hh = s >> 1;
        const int r0 = (s & 1) * 8;
        unsigned int lo0, lo1, hi0, hi1;
        if (hh == 0) {
          lo0 = pk2(sc[0][r0 + 0], sc[0][r0 + 1]); lo1 = pk2(sc[0][r0 + 2], sc[0][r0 + 3]);
          hi0 = pk2(sc[0][r0 + 4], sc[0][r0 + 5]); hi1 = pk2(sc[0][r0 + 6], sc[0][r0 + 7]);
        } else {
          lo0 = pk2(sc[1][r0 + 0], sc[1][r0 + 1]); lo1 = pk2(sc[1][r0 + 2], sc[1][r0 + 3]);
          hi0 = pk2(sc[1][r0 + 4], sc[1][r0 + 5]); hi1 = pk2(sc[1][r0 + 6], sc[1][r0 + 7]);
        }
        unsigned int s0 = half2 ? lo0 : hi0, s1 = half2 ? lo1 : hi1;
        unsigned int rc0 = (unsigned int)__shfl_xor((int)s0, 32);
        unsigned int rc1 = (unsigned int)__shfl_xor((int)s1, 32);
        u32x4 fr;
        fr[0] = half2 ? rc0 : lo0; fr[1] = half2 ? rc1 : lo1;
        fr[2] = half2 ? hi0 : rc0; fr[3] = half2 ? hi1 : rc1;
        bf16x8 pa = __builtin_bit_cast(bf16x8, fr);
#pragma unroll
        for (int d = 0; d < 4; d++) {
          int dd = d * 32 + l31;
          bf16x8 vf = *(const bf16x8*)(lv + dd * 128 + (((s * 2 + half2) ^ (dd & 7)) * 16));
          oacc[d] = __builtin_amdgcn_mfma_f32_32x32x16_bf16(pa, vf, oacc[d], 0, 0, 0);
        }
      }
    }
  }
  float inv = 1.0f / lsum;
#pragma unroll
  for (int r = 0; r < 16; r++) {
    int rr = (r & 3) + 8 * (r >> 2) + 4 * half2;
    float ir = __shfl(inv, rr);
    size_t ob = ((size_t)(b * SEQ + qw + rr)) * 2048 + h * HD;
#pragma unroll
    for (int d = 0; d < 4; d++)
      out[ob + d * 32 + l31] = f2bf(oacc[d][r] * ir);
  }
}

// ---------------- launcher -------------------------------------------------------------
extern "C" void kernel_launch(void* const* d_in, const int* in_sizes, int n_in,
                              void* d_out, int out_size, void* d_ws, size_t ws_size,
                              hipStream_t stream) {
  const float* x = (const float*)d_in[0];
  const float* cosT = (const float*)d_in[1];
  const float* sinT = (const float*)d_in[2];
  const float* wq = (const float*)d_in[3];
  const float* wk = (const float*)d_in[4];
  const float* wv = (const float*)d_in[5];
  const float* wo = (const float*)d_in[6];
  const float* wg = (const float*)d_in[7];
  const float* wu = (const float*)d_in[8];
  const float* wd = (const float*)d_in[9];
  const float* g1 = (const float*)d_in[10];
  const float* g2 = (const float*)d_in[11];
  float* out = (float*)d_out;
  char* ws = (char*)d_ws;

  unsigned short* wqkv = (unsigned short*)(ws + 0);
  unsigned short* hbuf = (unsigned short*)(ws + 16777216);
  unsigned short* qkv = (unsigned short*)(ws + 33554432);
  unsigned short* attn_o = (unsigned short*)(ws + 67108864);
  unsigned short* wo_bf = (unsigned short*)(ws + 83886080);
  unsigned short* wgu = (unsigned short*)(ws + 33554432);
  unsigned short* act = (unsigned short*)(ws + 92274688);
  unsigned short* wdown = (unsigned short*)(ws + 0);

  // ---- attention sub-block ----
  k_conv<<<2048, 256, 0, stream>>>(wq, wqkv);
  k_conv<<<1024, 256, 0, stream>>>(wk, wqkv + 4194304);
  k_conv<<<1024, 256, 0, stream>>>(wv, wqkv + 6291456);
  k_rmsnorm<<<4096, 256, 0, stream>>>(x, g1, hbuf);
  k_gemm8p<0><<<256, 512, 0, stream>>>(hbuf, wqkv, qkv, nullptr, nullptr,
                                       4096, 2048);
  k_rope<<<24576, 256, 0, stream>>>(qkv, cosT, sinT);
  k_attn2<<<512, 256, 0, stream>>>(qkv, attn_o);
  k_conv<<<2048, 256, 0, stream>>>(wo, wo_bf);
  k_gemm8<128, 1, 0><<<256, 512, 0, stream>>>(attn_o, wo_bf, nullptr, out, x,
                                              2048, 2048);
  // ---- SwiGLU MLP sub-block ----
  k_rmsnorm<<<4096, 256, 0, stream>>>(out, g2, hbuf);
  k_conv_gu<<<11008, 256, 0, stream>>>(wg, wu, wgu);
  k_gemm8p<2><<<688, 512, 0, stream>>>(hbuf, wgu, act, nullptr, nullptr,
                                       11008, 2048);
  k_conv<<<5504, 256, 0, stream>>>(wd, wdown);
  k_gemm8<128, 1, 0><<<256, 512, 0, stream>>>(act, wdown, nullptr, out, out,
                                              2048, 5504);
}

// Round 9
// 584.387 us; speedup vs baseline: 1.1831x; 1.0194x over previous
//
#include <hip/hip_runtime.h>

// LLM block: B=2,S=2048,D=2048,H=16,KVH=8,HD=128,FF=5504, f32 in/out, bf16 MFMA compute.
// Workspace layout (bytes), peak ~137MB:
//   wqkv_bf16   [4096,2048]  @ 0
//   h/h2_bf16   [4096,2048]  @ 16777216
//   qkv_bf16    [4096,4096]  @ 33554432   (region reused later by wgu)
//   attn_out    [4096,2048]  @ 67108864
//   wo_bf16     [2048,2048]  @ 83886080
//   wgu_bf16    [11008,2048] @ 33554432   (interleaved: per 256-row group = 128 gate | 128 up)
//   act_bf16    [4096,5504]  @ 92274688
//   wdown_bf16  [2048,5504]  @ 0          (converted late, after hbuf's final consumer)
//   x1 (f32 residual) lives in d_out.

#define DM 2048
#define SEQ 2048
#define HD 128
#define FF_ 5504
// 1/sqrt(128) * log2(e): attention runs softmax in exp2 domain.
#define QK_SCALE_L2E 0.12751744f

typedef __bf16 bf16x8 __attribute__((ext_vector_type(8)));
typedef float f32x4 __attribute__((ext_vector_type(4)));
typedef float f32x16 __attribute__((ext_vector_type(16)));
typedef unsigned short u16x8 __attribute__((ext_vector_type(8)));
typedef unsigned int u32x4 __attribute__((ext_vector_type(4)));

typedef __attribute__((address_space(1))) void* gas1;
typedef __attribute__((address_space(3))) void* las3;
#define GLDS16(g, s) __builtin_amdgcn_global_load_lds((gas1)(g), (las3)(s), 16, 0, 0)

static __device__ __forceinline__ float bf2f(unsigned short u) {
  union { unsigned int i; float f; } c; c.i = ((unsigned int)u) << 16; return c.f;
}
static __device__ __forceinline__ unsigned short f2bf(float f) {
  __bf16 b = (__bf16)f;
  return __builtin_bit_cast(unsigned short, b);
}
static __device__ __forceinline__ unsigned int pk2(float a, float b) {
  return (unsigned int)f2bf(a) | ((unsigned int)f2bf(b) << 16);
}
// native exp2 (v_exp_f32); __exp2f doesn't exist in HIP headers (r3 compile fail)
static __device__ __forceinline__ float fexp2(float x) { return exp2f(x); }

// ---------------- merged f32 -> bf16 weight convert (wq|wk|wv|wo), 1 row/block --------
__global__ __launch_bounds__(256) void k_convW(const float* __restrict__ wq,
                                               const float* __restrict__ wk,
                                               const float* __restrict__ wv,
                                               const float* __restrict__ wo,
                                               unsigned short* __restrict__ wqkv,
                                               unsigned short* __restrict__ wo_bf) {
  int b = blockIdx.x;
  const float* src;
  unsigned short* dst;
  if (b < 2048)      { src = wq + (size_t)b * DM;            dst = wqkv + (size_t)b * DM; }
  else if (b < 3072) { src = wk + (size_t)(b - 2048) * DM;   dst = wqkv + 4194304 + (size_t)(b - 2048) * DM; }
  else if (b < 4096) { src = wv + (size_t)(b - 3072) * DM;   dst = wqkv + 6291456 + (size_t)(b - 3072) * DM; }
  else               { src = wo + (size_t)(b - 4096) * DM;   dst = wo_bf + (size_t)(b - 4096) * DM; }
  int i = threadIdx.x * 8;
  float4 a = *(const float4*)&src[i];
  float4 c = *(const float4*)&src[i + 4];
  u16x8 o;
  o[0] = f2bf(a.x); o[1] = f2bf(a.y); o[2] = f2bf(a.z); o[3] = f2bf(a.w);
  o[4] = f2bf(c.x); o[5] = f2bf(c.y); o[6] = f2bf(c.z); o[7] = f2bf(c.w);
  *(u16x8*)&dst[i] = o;
}

// ---------------- plain convert (wd, late) ----------------
__global__ __launch_bounds__(256) void k_conv(const float* __restrict__ src,
                                              unsigned short* __restrict__ dst) {
  size_t i = (size_t)(blockIdx.x * 256 + threadIdx.x) * 8;
  float4 a = *(const float4*)&src[i];
  float4 b = *(const float4*)&src[i + 4];
  u16x8 o;
  o[0] = f2bf(a.x); o[1] = f2bf(a.y); o[2] = f2bf(a.z); o[3] = f2bf(a.w);
  o[4] = f2bf(b.x); o[5] = f2bf(b.y); o[6] = f2bf(b.z); o[7] = f2bf(b.w);
  *(u16x8*)&dst[i] = o;
}

// ---- gate/up interleaved convert: dst row r of group t: r<128 -> wg, else wu ----
__global__ __launch_bounds__(256) void k_conv_gu(const float* __restrict__ g,
                                                 const float* __restrict__ u,
                                                 unsigned short* __restrict__ dst) {
  int i = blockIdx.x * 256 + threadIdx.x;
  int row = i >> 8;
  int c8 = (i & 255) * 8;
  int t = row >> 8, r = row & 255;
  const float* src = (r < 128) ? (g + (size_t)(t * 128 + r) * DM + c8)
                               : (u + (size_t)(t * 128 + (r - 128)) * DM + c8);
  float4 a = *(const float4*)src;
  float4 b = *(const float4*)(src + 4);
  u16x8 o;
  o[0] = f2bf(a.x); o[1] = f2bf(a.y); o[2] = f2bf(a.z); o[3] = f2bf(a.w);
  o[4] = f2bf(b.x); o[5] = f2bf(b.y); o[6] = f2bf(b.z); o[7] = f2bf(b.w);
  *(u16x8*)&dst[(size_t)row * DM + c8] = o;
}

// ---------------- RMSNorm: one block per row (D=2048, 8 f32/thread) ----------------
__global__ __launch_bounds__(256) void k_rmsnorm(const float* __restrict__ x,
                                                 const float* __restrict__ g,
                                                 unsigned short* __restrict__ out) {
  int row = blockIdx.x, tid = threadIdx.x;
  const float* xr = x + (size_t)row * DM;
  float4 a = *(const float4*)&xr[tid * 8];
  float4 b = *(const float4*)&xr[tid * 8 + 4];
  float ss = a.x * a.x + a.y * a.y + a.z * a.z + a.w * a.w +
             b.x * b.x + b.y * b.y + b.z * b.z + b.w * b.w;
#pragma unroll
  for (int off = 32; off > 0; off >>= 1) ss += __shfl_xor(ss, off, 64);
  __shared__ float red[4];
  if ((tid & 63) == 0) red[tid >> 6] = ss;
  __syncthreads();
  float rs = rsqrtf((red[0] + red[1] + red[2] + red[3]) * (1.0f / DM) + 1e-5f);
  float4 ga = *(const float4*)&g[tid * 8];
  float4 gb = *(const float4*)&g[tid * 8 + 4];
  u16x8 o;
  o[0] = f2bf(a.x * rs * ga.x); o[1] = f2bf(a.y * rs * ga.y);
  o[2] = f2bf(a.z * rs * ga.z); o[3] = f2bf(a.w * rs * ga.w);
  o[4] = f2bf(b.x * rs * gb.x); o[5] = f2bf(b.y * rs * gb.y);
  o[6] = f2bf(b.z * rs * gb.z); o[7] = f2bf(b.w * rs * gb.w);
  *(u16x8*)&out[(size_t)row * DM + tid * 8] = o;
}

// ================= 8-phase GEMM (m201 port): C[M,N] = A[M,K]*Bt[N,K]^T ================
// BM=BN=256, BK=64, 512 thr (8 waves 2Mx4N), LDS 2 x 64KB (per-K-tile dbuf).
// r9: NO XCD swizzle (identity bid->tile). With round-robin bid->XCD, each XCD sees
// mt in {x, x+8} -> A panels (2MB) L2-resident; consecutive same-XCD blocks share nt
// -> B panel read ~once per pair. Halves L3 panel traffic vs r8's swizzle (which
// streamed all 16 mt per XCD). Schedule identical to r8 (verified).
// EPI: 0 plain bf16; 1 f32 res-add; 2 gateup-silu; 3 qkv with fused RoPE.
template <int EPI>
__global__ __launch_bounds__(512, 1) void k_gemm8p(
    const unsigned short* __restrict__ A, const unsigned short* __restrict__ Bt,
    unsigned short* __restrict__ outB, float* __restrict__ outF,
    const float* __restrict__ res, int N, int K,
    const float* __restrict__ cosT, const float* __restrict__ sinT) {
  __shared__ __attribute__((aligned(16))) unsigned char smem[2][65536];
  const int tid = threadIdx.x, w = tid >> 6, l = tid & 63;
  const int wr = w >> 2, wc = w & 3, lr = l & 15, lg = l >> 4;
  const int bswz = blockIdx.x;                            // identity (no XCD swizzle)
  const int mt = bswz & 15, nt = bswz >> 4;
  const int m0 = mt * 256, n0 = nt * 256;
  const int nkt = K >> 6;

  const int rA0 = tid >> 3;
  const int rB0 = ((tid >> 8) << 6) + ((tid >> 3) & 31);
  const int sc = ((tid & 7) ^ ((tid >> 3) & 7)) * 8;      // pre-swizzled source chunk
  const unsigned short* Abase = A + (size_t)(m0 + rA0) * K + sc;
  const unsigned short* Bbase = Bt + (size_t)(n0 + rB0) * K + sc;

  auto stA = [&](int kt, int h) {
    unsigned char* dst = smem[kt & 1] + h * 16384;
    const unsigned short* s = Abase + (size_t)(h * 64) * K + kt * 64;
    GLDS16(s, dst + tid * 16);
    GLDS16(s + (size_t)128 * K, dst + (512 + tid) * 16);
  };
  auto stB = [&](int kt, int h) {
    unsigned char* dst = smem[kt & 1] + 32768 + h * 16384;
    const unsigned short* s = Bbase + (size_t)(h * 32) * K + kt * 64;
    GLDS16(s, dst + tid * 16);
    GLDS16(s + (size_t)128 * K, dst + (512 + tid) * 16);
  };

  const int aRow = (wr * 64 + lr) * 128;
  const int bRow = (wc * 32 + lr) * 128;
  const int axr = lr & 7;
#define RDA(BUF, M, KK)                                                        \
  (*(const bf16x8*)((BUF) + ((M) >> 2) * 16384 + aRow + ((M) & 3) * 2048 +     \
                    ((((KK) * 4 + lg) ^ axr) << 4)))
#define RDB(BUF, NN, KK)                                                       \
  (*(const bf16x8*)((BUF) + 32768 + ((NN) >> 1) * 16384 + bRow +               \
                    ((NN) & 1) * 2048 + ((((KK) * 4 + lg) ^ axr) << 4)))

  f32x4 acc[8][4] = {};
  bf16x8 aq[4][2], bq0[2][2], bq1[2][2];

  stA(0, 0); stB(0, 0); stB(0, 1); stA(0, 1);
  asm volatile("s_waitcnt vmcnt(4)" ::: "memory");
  __builtin_amdgcn_s_barrier();

#define MMQ(MB, NB, BQ)                                                        \
  _Pragma("unroll") for (int m = 0; m < 4; m++)                                \
    _Pragma("unroll") for (int n = 0; n < 2; n++)                              \
      _Pragma("unroll") for (int kk = 0; kk < 2; kk++)                         \
          acc[(MB) + m][(NB) + n] = __builtin_amdgcn_mfma_f32_16x16x32_bf16(   \
              aq[m][kk], BQ[n][kk], acc[(MB) + m][(NB) + n], 0, 0, 0);

#define KT8(KT, ST, W1, W2, HASW4)                                             \
  {                                                                            \
    const unsigned char* buf = smem[(KT) & 1];                                 \
    /* ---- phase 1 ---- */                                                    \
    _Pragma("unroll") for (int m = 0; m < 4; m++)                              \
      _Pragma("unroll") for (int kk = 0; kk < 2; kk++)                         \
          aq[m][kk] = RDA(buf, m, kk);                                         \
    _Pragma("unroll") for (int n = 0; n < 2; n++)                              \
      _Pragma("unroll") for (int kk = 0; kk < 2; kk++)                         \
          bq0[n][kk] = RDB(buf, n, kk);                                        \
    if (ST) stA((KT) + 1, 0);                                                  \
    __builtin_amdgcn_s_barrier();                                              \
    asm volatile("s_waitcnt lgkmcnt(0)" ::: "memory");                         \
    __builtin_amdgcn_sched_barrier(0);                                         \
    __builtin_amdgcn_s_setprio(1);                                             \
    MMQ(0, 0, bq0)                                                             \
    __builtin_amdgcn_s_setprio(0);                                             \
    asm volatile("s_waitcnt vmcnt(%0)" ::"i"(W1) : "memory");                  \
    __builtin_amdgcn_s_barrier();                                              \
    /* ---- phase 2 ---- */                                                    \
    _Pragma("unroll") for (int n = 0; n < 2; n++)                              \
      _Pragma("unroll") for (int kk = 0; kk < 2; kk++)                         \
          bq1[n][kk] = RDB(buf, n + 2, kk);                                    \
    if (ST) stB((KT) + 1, 0);                                                  \
    __builtin_amdgcn_s_barrier();                                              \
    asm volatile("s_waitcnt lgkmcnt(0)" ::: "memory");                         \
    __builtin_amdgcn_sched_barrier(0);                                         \
    __builtin_amdgcn_s_setprio(1);                                             \
    MMQ(0, 2, bq1)                                                             \
    __builtin_amdgcn_s_setprio(0);                                             \
    asm volatile("s_waitcnt vmcnt(%0)" ::"i"(W2) : "memory");                  \
    __builtin_amdgcn_s_barrier();                                              \
    /* ---- phase 3 ---- */                                                    \
    _Pragma("unroll") for (int m = 0; m < 4; m++)                              \
      _Pragma("unroll") for (int kk = 0; kk < 2; kk++)                         \
          aq[m][kk] = RDA(buf, m + 4, kk);                                     \
    if (ST) stB((KT) + 1, 1);                                                  \
    __builtin_amdgcn_s_barrier();                                              \
    asm volatile("s_waitcnt lgkmcnt(0)" ::: "memory");                         \
    __builtin_amdgcn_sched_barrier(0);                                         \
    __builtin_amdgcn_s_setprio(1);                                             \
    MMQ(4, 2, bq1)                                                             \
    __builtin_amdgcn_s_setprio(0);                                             \
    __builtin_amdgcn_s_barrier();                                              \
    /* ---- phase 4 ---- */                                                    \
    if (ST) stA((KT) + 1, 1);                                                  \
    __builtin_amdgcn_s_barrier();                                              \
    __builtin_amdgcn_s_setprio(1);                                             \
    MMQ(4, 0, bq0)                                                             \
    __builtin_amdgcn_s_setprio(0);                                             \
    if (HASW4) asm volatile("s_waitcnt vmcnt(4)" ::: "memory");                \
    __builtin_amdgcn_s_barrier();                                              \
  }

  for (int kt = 0; kt < nkt - 1; kt++) KT8(kt, true, 4, 4, true);
  KT8(nkt - 1, false, 2, 0, false);
#undef KT8
#undef MMQ
#undef RDA
#undef RDB

  const int rbase = wr * 128 + lg * 4;
  const int cbase = wc * 64 + lr;
  if constexpr (EPI == 0) {
#pragma unroll
    for (int m = 0; m < 8; m++)
#pragma unroll
      for (int n = 0; n < 4; n++)
#pragma unroll
        for (int j = 0; j < 4; j++)
          outB[(size_t)(m0 + rbase + m * 16 + j) * N + n0 + cbase + n * 16] =
              f2bf(acc[m][n][j]);
  } else if constexpr (EPI == 1) {
#pragma unroll
    for (int m = 0; m < 8; m++)
#pragma unroll
      for (int n = 0; n < 4; n++)
#pragma unroll
        for (int j = 0; j < 4; j++) {
          size_t o = (size_t)(m0 + rbase + m * 16 + j) * N + n0 + cbase + n * 16;
          outF[o] = res[o] + acc[m][n][j];
        }
  } else if constexpr (EPI == 2) {
    // gateup: silu(gate)*up via 64KB f32 LDS scratch, two 128-row halves.
    float* gl = (float*)smem;
    const int ab = n0 >> 1;
    __syncthreads();
#pragma unroll
    for (int half = 0; half < 2; half++) {
      if (wr == half && wc < 2) {
#pragma unroll
        for (int m = 0; m < 8; m++)
#pragma unroll
          for (int n = 0; n < 4; n++)
#pragma unroll
            for (int j = 0; j < 4; j++)
              gl[(m * 16 + lg * 4 + j) * 128 + wc * 64 + n * 16 + lr] = acc[m][n][j];
      }
      __syncthreads();
      if (wr == half && wc >= 2) {
#pragma unroll
        for (int m = 0; m < 8; m++)
#pragma unroll
          for (int n = 0; n < 4; n++)
#pragma unroll
            for (int j = 0; j < 4; j++) {
              int rl = m * 16 + lg * 4 + j;
              int cl = (wc - 2) * 64 + n * 16 + lr;
              float g = gl[rl * 128 + cl];
              float s = g / (1.0f + __expf(-g));
              outB[(size_t)(m0 + half * 128 + rl) * FF_ + ab + cl] = f2bf(s * acc[m][n][j]);
            }
      }
      __syncthreads();
    }
  } else {
    // EPI==3: QKV epilogue with fused RoPE. nt<8: q heads (rope*scale); nt 8..11:
    // k heads (rope); nt>=12: v (plain). Pair (d, d^64) exchanged via LDS [2][16][256].
    if (nt >= 12) {
#pragma unroll
      for (int m = 0; m < 8; m++)
#pragma unroll
        for (int n = 0; n < 4; n++)
#pragma unroll
          for (int j = 0; j < 4; j++)
            outB[(size_t)(m0 + rbase + m * 16 + j) * N + n0 + cbase + n * 16] =
                f2bf(acc[m][n][j]);
    } else {
      float* gl = (float*)smem;           // [2][16][256] f32 = 32KB
      const float qs = (nt < 8) ? QK_SCALE_L2E : 1.0f;
      __syncthreads();
      for (int m = 0; m < 8; m++) {
#pragma unroll
        for (int n = 0; n < 4; n++)
#pragma unroll
          for (int j = 0; j < 4; j++)
            gl[wr * 4096 + (lg * 4 + j) * 256 + wc * 64 + n * 16 + lr] = acc[m][n][j];
        __syncthreads();
#pragma unroll
        for (int n = 0; n < 4; n++)
#pragma unroll
          for (int j = 0; j < 4; j++) {
            int c = wc * 64 + n * 16 + lr;
            int d = c & 127;
            int row = m0 + wr * 128 + m * 16 + lg * 4 + j;
            int s = row & (SEQ - 1);
            float own = acc[m][n][j];
            float prt = gl[wr * 4096 + (lg * 4 + j) * 256 + (c ^ 64)];
            float cv = cosT[s * HD + d], sv = sinT[s * HD + d];
            float rot = own * cv + ((d & 64) ? prt : -prt) * sv;
            outB[(size_t)row * N + n0 + c] = f2bf(rot * qs);
          }
        __syncthreads();
      }
    }
  }
}

// ---------------- r5 counted-vmcnt GEMM (BK=32, 4 buffers) for WO / down --------------
template <int BN, int EPI>
__global__ __launch_bounds__(512, 2) void k_gemm8(
    const unsigned short* __restrict__ A, const unsigned short* __restrict__ Bt,
    unsigned short* __restrict__ outB, float* __restrict__ outF,
    const float* __restrict__ res, int N, int K) {
  constexpr int NF = BN / 64;
  constexpr int BSTMT = BN / 128;
  constexpr int ABY = 256 * 64;
  constexpr int BBY = BN * 64;
  constexpr int BUF = ABY + BBY;
  constexpr int VPK = 2 + BSTMT;
  __shared__ __attribute__((aligned(16))) unsigned char smem[4 * BUF];

  const int tid = threadIdx.x, w = tid >> 6, l = tid & 63;
  const int wr = w >> 2, wc = w & 3, lr = l & 15, lg = l >> 4;
  const int bswz = blockIdx.x;                            // identity (no XCD swizzle)
  const int mt = bswz & 15, nt = bswz >> 4;
  const int m0 = mt * 256, n0 = nt * BN;
  const int nk = K >> 5;

  const int srow = w * 16 + (l >> 2);
  const int sg8 = ((l & 3) ^ ((l >> 3) & 3)) * 8;
  const unsigned short* Asrc = A + (size_t)(m0 + srow) * K + sg8;
  const unsigned short* Bsrc = Bt + (size_t)(n0 + srow) * K + sg8;
  const int aoff = (wr * 128 + lr) * 64 + ((lg ^ ((lr >> 1) & 3)) << 4);
  const int boff = (wc * (BN / 4) + lr) * 64 + ((lg ^ ((lr >> 1) & 3)) << 4);

  auto stageA = [&](int kt) {
    unsigned char* bb = smem + (kt & 3) * BUF;
#pragma unroll
    for (int i = 0; i < 2; i++)
      GLDS16(Asrc + (size_t)i * 128 * K + kt * 32, bb + (i * 512 + w * 64) * 16);
  };
  auto stageB = [&](int kt) {
    unsigned char* bb = smem + (kt & 3) * BUF + ABY;
#pragma unroll
    for (int i = 0; i < BSTMT; i++)
      GLDS16(Bsrc + (size_t)i * 128 * K + kt * 32, bb + (i * 512 + w * 64) * 16);
  };

  f32x4 acc[8][NF] = {};

  for (int kt = 0; kt < 3; kt++) { stageA(kt); stageB(kt); }
  asm volatile("s_waitcnt vmcnt(%0)" ::"i"(2 * VPK) : "memory");
  __builtin_amdgcn_s_barrier();
  for (int kt = 0; kt < nk; kt++) {
    unsigned char* ba = smem + (kt & 3) * BUF;
    unsigned char* bb = ba + ABY;
    const bool st = (kt + 3) < nk;
    bf16x8 am[8], bnf[NF];
#pragma unroll
    for (int m = 0; m < 8; m++) am[m] = *(const bf16x8*)(ba + aoff + m * 1024);
#pragma unroll
    for (int n = 0; n < NF; n++) bnf[n] = *(const bf16x8*)(bb + boff + n * 1024);
    if (st) { stageA(kt + 3); stageB(kt + 3); }
    __builtin_amdgcn_s_barrier();
    __builtin_amdgcn_s_setprio(1);
#pragma unroll
    for (int m = 0; m < 8; m++)
#pragma unroll
      for (int n = 0; n < NF; n++)
        acc[m][n] = __builtin_amdgcn_mfma_f32_16x16x32_bf16(am[m], bnf[n], acc[m][n], 0, 0, 0);
    __builtin_amdgcn_s_setprio(0);
    if (kt <= nk - 4)      asm volatile("s_waitcnt vmcnt(%0)" ::"i"(2 * VPK) : "memory");
    else if (kt == nk - 3) asm volatile("s_waitcnt vmcnt(%0)" ::"i"(VPK) : "memory");
    else if (kt == nk - 2) asm volatile("s_waitcnt vmcnt(0)" ::: "memory");
    __builtin_amdgcn_s_barrier();
  }

  const int rbase = wr * 128 + lg * 4;
  const int cbase = wc * (BN / 4) + lr;
  if constexpr (EPI == 0) {
#pragma unroll
    for (int m = 0; m < 8; m++)
#pragma unroll
      for (int n = 0; n < NF; n++)
#pragma unroll
        for (int j = 0; j < 4; j++)
          outB[(size_t)(m0 + rbase + m * 16 + j) * N + n0 + cbase + n * 16] =
              f2bf(acc[m][n][j]);
  } else {
#pragma unroll
    for (int m = 0; m < 8; m++)
#pragma unroll
      for (int n = 0; n < NF; n++)
#pragma unroll
        for (int j = 0; j < 4; j++) {
          size_t o = (size_t)(m0 + rbase + m * 16 + j) * N + n0 + cbase + n * 16;
          outF[o] = res[o] + acc[m][n][j];
        }
  }
}

// ---------------- causal GQA flash attention, 32x32 swapped-QK structure --------------
__global__ __launch_bounds__(256) void k_attn2(const unsigned short* __restrict__ qkv,
                                               unsigned short* __restrict__ out) {
  __shared__ __attribute__((aligned(16))) unsigned short lK[2][64 * 128];
  __shared__ __attribute__((aligned(16))) unsigned short lV[2][128 * 64];
  const float NEG = -3.0e38f;
  int bx = blockIdx.x;
  int qtile = 15 - (bx >> 5);          // heaviest q-tiles dispatched first
  int hb = bx & 31;
  int h = hb & 15, b = hb >> 4;
  int q0 = qtile * 128;
  int tid = threadIdx.x, w = tid >> 6, l = tid & 63;
  int l31 = l & 31, half2 = l >> 5;
  const unsigned short* base = qkv + (size_t)b * SEQ * 4096;
  const unsigned short* Kp = base + 2048 + (h >> 1) * HD;
  const unsigned short* Vp = base + 3072 + (h >> 1) * HD;
  const int qw = q0 + w * 32;

  bf16x8 qf[8];
  {
    const unsigned short* qrow = base + (size_t)(qw + l31) * 4096 + h * HD + half2 * 8;
#pragma unroll
    for (int d = 0; d < 8; d++) qf[d] = *(const bf16x8*)(qrow + d * 16);
  }

  f32x16 oacc[4] = {};
  float mrow = NEG, lsum = 0.0f;

  const int vp = tid & 31, vdc = tid >> 5;
  u16x8 va0, va1, vb0, vb1;

  auto stageK = [&](int t) {
    unsigned char* dst = (unsigned char*)lK[t & 1];
#pragma unroll
    for (int i = 0; i < 4; i++) {
      int c = i * 256 + tid;
      int row = c >> 4;
      int g = (c & 15) ^ (row & 7);
      GLDS16(Kp + (size_t)(t * 64 + row) * 4096 + g * 8, dst + (i * 256 + w * 64) * 16);
    }
  };
  auto loadV = [&](int t) {
    const unsigned short* vr = Vp + (size_t)(t * 64 + vp * 2) * 4096 + vdc * 16;
    va0 = *(const u16x8*)(vr);
    va1 = *(const u16x8*)(vr + 8);
    vb0 = *(const u16x8*)(vr + 4096);
    vb1 = *(const u16x8*)(vr + 4096 + 8);
  };

  const int nt = (q0 >> 6) + 2;
  stageK(0);
  loadV(0);

  for (int t = 0; t < nt; t++) {
    __syncthreads();
    {
      unsigned char* lv = (unsigned char*)lV[t & 1];
#pragma unroll
      for (int j = 0; j < 16; j++) {
        int dd = vdc * 16 + j;
        unsigned short lo = (j < 8) ? va0[j] : va1[j - 8];
        unsigned short hi = (j < 8) ? vb0[j] : vb1[j - 8];
        unsigned int pkv = (unsigned int)lo | ((unsigned int)hi << 16);
        *(unsigned int*)(lv + dd * 128 + (((vp >> 2) ^ (dd & 7)) * 16) + (vp & 3) * 4) = pkv;
      }
    }
    __syncthreads();
    if (t + 1 < nt) { stageK(t + 1); loadV(t + 1); }
    const int kv0 = t * 64;
    if (kv0 <= qw + 31) {
      f32x16 sc[2] = {};
      const unsigned char* lk = (const unsigned char*)lK[t & 1];
#pragma unroll
      for (int hh = 0; hh < 2; hh++) {
        int kk = hh * 32 + l31;
        const unsigned char* krow = lk + kk * 256;
#pragma unroll
        for (int d = 0; d < 8; d++) {
          bf16x8 kf = *(const bf16x8*)(krow + (((d * 2 + half2) ^ (kk & 7)) * 16));
          sc[hh] = __builtin_amdgcn_mfma_f32_32x32x16_bf16(kf, qf[d], sc[hh], 0, 0, 0);
        }
      }
      const int qa = qw + l31;
      if (kv0 + 63 > qw) {
#pragma unroll
        for (int hh = 0; hh < 2; hh++)
#pragma unroll
          for (int r = 0; r < 16; r++) {
            int kva = kv0 + hh * 32 + (r & 3) + 8 * (r >> 2) + 4 * half2;
            if (kva > qa) sc[hh][r] = NEG;
          }
      }
      float mx = sc[0][0];
#pragma unroll
      for (int r = 1; r < 16; r++) mx = fmaxf(mx, sc[0][r]);
#pragma unroll
      for (int r = 0; r < 16; r++) mx = fmaxf(mx, sc[1][r]);
      mx = fmaxf(mx, __shfl_xor(mx, 32));
      bool ok = (mx <= mrow + 11.0f);
      if (__ballot(ok) != ~0ull) {
        float mnew = fmaxf(mrow, mx);
        float fct = fexp2(mrow - mnew);
        mrow = mnew;
        lsum *= fct;
#pragma unroll
        for (int r = 0; r < 16; r++) {
          int rr = (r & 3) + 8 * (r >> 2) + 4 * half2;
          float fr = __shfl(fct, rr);
#pragma unroll
          for (int d = 0; d < 4; d++) oacc[d][r] *= fr;
        }
      }
      float ps = 0.0f;
#pragma unroll
      for (int hh = 0; hh < 2; hh++)
#pragma unroll
        for (int r = 0; r < 16; r++) {
          float e = fexp2(sc[hh][r] - mrow);
          sc[hh][r] = e;
          ps += e;
        }
      ps += __shfl_xor(ps, 32);
      lsum += ps;
      const unsigned char* lv = (const unsigned char*)lV[t & 1];
#pragma unroll
      for (int s = 0; s < 4; s++) {
        const int hh = s >> 1;
        const int r0 = (s & 1) * 8;
        unsigned int lo0, lo1, hi0, hi1;
        if (hh == 0) {
          lo0 = pk2(sc[0][r0 + 0], sc[0][r0 + 1]); lo1 = pk2(sc[0][r0 + 2], sc[0][r0 + 3]);
          hi0 = pk2(sc[0][r0 + 4], sc[0][r0 + 5]); hi1 = pk2(sc[0][r0 + 6], sc[0][r0 + 7]);
        } else {
          lo0 = pk2(sc[1][r0 + 0], sc[1][r0 + 1]); lo1 = pk2(sc[1][r0 + 2], sc[1][r0 + 3]);
          hi0 = pk2(sc[1][r0 + 4], sc[1][r0 + 5]); hi1 = pk2(sc[1][r0 + 6], sc[1][r0 + 7]);
        }
        unsigned int s0 = half2 ? lo0 : hi0, s1 = half2 ? lo1 : hi1;
        unsigned int rc0 = (unsigned int)__shfl_xor((int)s0, 32);
        unsigned int rc1 = (unsigned int)__shfl_xor((int)s1, 32);
        u32x4 fr;
        fr[0] = half2 ? rc0 : lo0; fr[1] = half2 ? rc1 : lo1;
        fr[2] = half2 ? hi0 : rc0; fr[3] = half2 ? hi1 : rc1;
        bf16x8 pa = __builtin_bit_cast(bf16x8, fr);
#pragma unroll
        for (int d = 0; d < 4; d++) {
          int dd = d * 32 + l31;
          bf16x8 vf = *(const bf16x8*)(lv + dd * 128 + (((s * 2 + half2) ^ (dd & 7)) * 16));
          oacc[d] = __builtin_amdgcn_mfma_f32_32x32x16_bf16(pa, vf, oacc[d], 0, 0, 0);
        }
      }
    }
  }
  float inv = 1.0f / lsum;
#pragma unroll
  for (int r = 0; r < 16; r++) {
    int rr = (r & 3) + 8 * (r >> 2) + 4 * half2;
    float ir = __shfl(inv, rr);
    size_t ob = ((size_t)(b * SEQ + qw + rr)) * 2048 + h * HD;
#pragma unroll
    for (int d = 0; d < 4; d++)
      out[ob + d * 32 + l31] = f2bf(oacc[d][r] * ir);
  }
}

// ---------------- launcher -------------------------------------------------------------
extern "C" void kernel_launch(void* const* d_in, const int* in_sizes, int n_in,
                              void* d_out, int out_size, void* d_ws, size_t ws_size,
                              hipStream_t stream) {
  const float* x = (const float*)d_in[0];
  const float* cosT = (const float*)d_in[1];
  const float* sinT = (const float*)d_in[2];
  const float* wq = (const float*)d_in[3];
  const float* wk = (const float*)d_in[4];
  const float* wv = (const float*)d_in[5];
  const float* wo = (const float*)d_in[6];
  const float* wg = (const float*)d_in[7];
  const float* wu = (const float*)d_in[8];
  const float* wd = (const float*)d_in[9];
  const float* g1 = (const float*)d_in[10];
  const float* g2 = (const float*)d_in[11];
  float* out = (float*)d_out;
  char* ws = (char*)d_ws;

  unsigned short* wqkv = (unsigned short*)(ws + 0);
  unsigned short* hbuf = (unsigned short*)(ws + 16777216);
  unsigned short* qkv = (unsigned short*)(ws + 33554432);
  unsigned short* attn_o = (unsigned short*)(ws + 67108864);
  unsigned short* wo_bf = (unsigned short*)(ws + 83886080);
  unsigned short* wgu = (unsigned short*)(ws + 33554432);
  unsigned short* act = (unsigned short*)(ws + 92274688);
  unsigned short* wdown = (unsigned short*)(ws + 0);

  // ---- attention sub-block ----
  k_convW<<<6144, 256, 0, stream>>>(wq, wk, wv, wo, wqkv, wo_bf);
  k_rmsnorm<<<4096, 256, 0, stream>>>(x, g1, hbuf);
  k_gemm8p<3><<<256, 512, 0, stream>>>(hbuf, wqkv, qkv, nullptr, nullptr,
                                       4096, 2048, cosT, sinT);
  k_attn2<<<512, 256, 0, stream>>>(qkv, attn_o);
  k_gemm8<128, 1><<<256, 512, 0, stream>>>(attn_o, wo_bf, nullptr, out, x,
                                           2048, 2048);
  // ---- SwiGLU MLP sub-block ----
  k_rmsnorm<<<4096, 256, 0, stream>>>(out, g2, hbuf);
  k_conv_gu<<<11008, 256, 0, stream>>>(wg, wu, wgu);
  k_gemm8p<2><<<688, 512, 0, stream>>>(hbuf, wgu, act, nullptr, nullptr,
                                       11008, 2048, nullptr, nullptr);
  k_conv<<<5504, 256, 0, stream>>>(wd, wdown);
  k_gemm8<128, 1><<<256, 512, 0, stream>>>(act, wdown, nullptr, out, out,
                                           2048, 5504);
}